// Round 15
// baseline (666.779 us; speedup 1.0000x reference)
//
#include <hip/hip_runtime.h>
#include <stdint.h>

#define C_   128
#define H_   128
#define W_   128
#define HW_  (128*128)

// sc/pbf per-scale element offsets (s3 first, then s2, s1, s0)
#define SC_OFF3 0
#define SC_OFF2 4194304
#define SC_OFF1 4456448
#define SC_OFF0 4472832
#define SC_TOT  4473856

typedef unsigned short ushort_t;
typedef __attribute__((ext_vector_type(8)))  short bf16x8;
typedef __attribute__((ext_vector_type(16))) float f32x16;

__device__ __forceinline__ float bf2f(uint32_t u) {
    union { float f; uint32_t i; } v; v.i = u << 16; return v.f;
}
__device__ __forceinline__ uint32_t f2bf(float f) {
    union { float f; uint32_t i; } v; v.f = f;
    uint32_t u = v.i;
    uint32_t r = u + 0x7FFFu + ((u >> 16) & 1u);
    return r >> 16;  // RTNE bf16 bits in low 16
}
__device__ __forceinline__ void async16(const ushort_t* g, void* l) {
    __builtin_amdgcn_global_load_lds(
        (const __attribute__((address_space(1))) unsigned int*)g,
        (__attribute__((address_space(3))) unsigned int*)l, 16, 0, 0);
}

// NHWC-p layout: element (img, h, c, w) at ((img*128+h)*8 + (c>>4))*2048 + w*16 + (c&15)
// attn scale-chunk NCHW: ((scale*16+img)*32 + c_local)*16384 + h*128 + w (aliases qw)
// windowed layout per scale: base = scale*8388608 + ((b*Ntok + tok)*Dd + dd)
// V^T (vt, aliases kw): vt + scale*8388608 + (b*Dd + dd)*n + tok

// ---------------------------------------------------------------------------
// prepack conv weights -> MFMA A-fragment-linear order (bf16).
// ---------------------------------------------------------------------------
__global__ __launch_bounds__(256) void prepack_kernel(
    const float* __restrict__ Wo, const float* __restrict__ Wf1,
    const float* __restrict__ Wf2, ushort_t* __restrict__ Wp)
{
    int t = blockIdx.x * 256 + threadIdx.x;          // 0..147455
    const float* W = (blockIdx.y == 0) ? Wo : ((blockIdx.y == 1) ? Wf1 : Wf2);
    ushort_t* dst = Wp + (size_t)blockIdx.y * 147456;
    int j = t & 7, lane = (t >> 3) & 63, f = t >> 9;
    int cot = f & 3, s = (f >> 2) & 1, tap = (f >> 3) % 9, cc = f / 72;
    int co = cot * 32 + (lane & 31);
    int ci = cc * 32 + s * 16 + (lane >> 5) * 8 + j;
    dst[t] = (ushort_t)f2bf(W[((size_t)co * 128 + ci) * 9 + tap]);
}

// ---------------------------------------------------------------------------
// prepack 1x1 qkv weights -> A-fragment-linear (bf16). grid (64, 3).
// ---------------------------------------------------------------------------
__global__ __launch_bounds__(256) void prepack1_kernel(
    const float* __restrict__ Wq, const float* __restrict__ Wk,
    const float* __restrict__ Wv, ushort_t* __restrict__ Wqkv)
{
    int t = blockIdx.x * 256 + threadIdx.x;          // 0..16383
    const float* W = (blockIdx.y == 0) ? Wq : ((blockIdx.y == 1) ? Wk : Wv);
    ushort_t* dst = Wqkv + (size_t)blockIdx.y * 16384;
    int j = t & 7, lane = (t >> 3) & 63, f = t >> 9;  // f 0..31
    int cot = f & 3, s = f >> 2;
    int co = cot * 32 + (lane & 31);
    int ci = s * 16 + (lane >> 5) * 8 + j;
    dst[t] = (ushort_t)f2bf(W[(size_t)co * 128 + ci]);
}

// ---------------------------------------------------------------------------
// NCHW fp32 -> NHWC-p bf16 (for x). grid (128, 16).
// ---------------------------------------------------------------------------
__global__ __launch_bounds__(256) void nchw2nhwc_kernel(
    const float* __restrict__ in, ushort_t* __restrict__ out)
{
    __shared__ ushort_t tile[128 * 136];
    const int img = blockIdx.y, hh = blockIdx.x;
    const int tid = threadIdx.x;
    #pragma unroll
    for (int i = 0; i < 8; ++i) {
        int idx = tid + 256 * i;
        int c = idx >> 4, w8 = (idx & 15) * 8;
        size_t src = ((size_t)img * 128 + c) * (size_t)HW_ + hh * 128 + w8;
        const float4* fp = (const float4*)&in[src];
        float4 f0 = fp[0], f1 = fp[1];
        ushort_t v[8];
        v[0] = (ushort_t)f2bf(f0.x); v[1] = (ushort_t)f2bf(f0.y);
        v[2] = (ushort_t)f2bf(f0.z); v[3] = (ushort_t)f2bf(f0.w);
        v[4] = (ushort_t)f2bf(f1.x); v[5] = (ushort_t)f2bf(f1.y);
        v[6] = (ushort_t)f2bf(f1.z); v[7] = (ushort_t)f2bf(f1.w);
        #pragma unroll
        for (int k = 0; k < 8; ++k) {
            int w = w8 + k;
            int g = (c >> 3) ^ ((w >> 3) & 7);
            tile[w * 136 + g * 8 + (c & 7)] = v[k];
        }
    }
    __syncthreads();
    #pragma unroll
    for (int i = 0; i < 8; ++i) {
        int idx = tid + 256 * i;
        int w = idx >> 4, g = idx & 15;
        int gs = g ^ ((w >> 3) & 7);
        uint4 raw = *(const uint4*)&tile[w * 136 + gs * 8];
        int c8 = g * 8;
        size_t off = (((size_t)(img * 128 + hh)) * 8 + (c8 >> 4)) * 2048 + w * 16 + (c8 & 8);
        *(uint4*)&out[off] = raw;
    }
}

// ---------------------------------------------------------------------------
// attn scale-chunk NCHW (bf16) -> NHWC-p bf16. grid (128, 16).
// ---------------------------------------------------------------------------
__global__ __launch_bounds__(256) void attn2nhwc_kernel(
    const ushort_t* __restrict__ in, ushort_t* __restrict__ out)
{
    __shared__ ushort_t tile[128 * 136];
    const int img = blockIdx.y, hh = blockIdx.x;
    const int tid = threadIdx.x;
    #pragma unroll
    for (int i = 0; i < 8; ++i) {
        int idx = tid + 256 * i;
        int c = idx >> 4, w8 = (idx & 15) * 8;
        size_t src = (((size_t)((c >> 5) * 16 + img)) * 32 + (c & 31)) * (size_t)HW_
                     + hh * 128 + w8;
        uint4 raw = *(const uint4*)&in[src];
        ushort_t v[8];
        v[0] = raw.x & 0xffffu; v[1] = raw.x >> 16;
        v[2] = raw.y & 0xffffu; v[3] = raw.y >> 16;
        v[4] = raw.z & 0xffffu; v[5] = raw.z >> 16;
        v[6] = raw.w & 0xffffu; v[7] = raw.w >> 16;
        #pragma unroll
        for (int k = 0; k < 8; ++k) {
            int w = w8 + k;
            int g = (c >> 3) ^ ((w >> 3) & 7);
            tile[w * 136 + g * 8 + (c & 7)] = v[k];
        }
    }
    __syncthreads();
    #pragma unroll
    for (int i = 0; i < 8; ++i) {
        int idx = tid + 256 * i;
        int w = idx >> 4, g = idx & 15;
        int gs = g ^ ((w >> 3) & 7);
        uint4 raw = *(const uint4*)&tile[w * 136 + gs * 8];
        int c8 = g * 8;
        size_t off = (((size_t)(img * 128 + hh)) * 8 + (c8 >> 4)) * 2048 + w * 16 + (c8 & 8);
        *(uint4*)&out[off] = raw;
    }
}

// ---------------------------------------------------------------------------
// qkv MFMA v4: fused q+k+v, 768 threads, depth-2 prefetch, LDS-repacked
// coalesced epilogue (uint4 runs; all scales have psz >= 8).
// grid (128, 16), block 768.
// ---------------------------------------------------------------------------
__global__ __launch_bounds__(768, 1) void qkvm_kernel(
    const ushort_t* __restrict__ xn, const ushort_t* __restrict__ Wqkv,
    const float* __restrict__ bq, const float* __restrict__ bk,
    const float* __restrict__ bv,
    ushort_t* __restrict__ qw, ushort_t* __restrict__ kw,
    ushort_t* __restrict__ vw)
{
    // staging: 3 bufs x 2048 (12 KB) | epilogue tiles: 3 w3 x 2 coh x 4096 (48 KB)
    __shared__ ushort_t lds[24576];
    const int h = blockIdx.x, img = blockIdx.y;
    const int tid = threadIdx.x, lane = tid & 63, wv = tid >> 6;
    const int w3 = wv >> 2, iw = wv & 3;
    const int pxh = iw & 1, coh = iw >> 1;
    const int kch = lane >> 5;
    const ushort_t* Wb = Wqkv + (size_t)w3 * 16384;
    const float* bias = (w3 == 0) ? bq : ((w3 == 1) ? bk : bv);
    const int b_ = img >> 2, t_ = img & 3;

    f32x16 acc[2][2];
    #pragma unroll
    for (int i = 0; i < 2; ++i)
        #pragma unroll
        for (int j = 0; j < 2; ++j)
            #pragma unroll
            for (int k = 0; k < 16; ++k) acc[i][j][k] = 0.f;

    auto STAGE = [&](int p, int b) {
        if (w3 == 0) {
            int kb = iw;
            int px = kb * 32 + (lane >> 1), ch = lane & 1;
            int cg = ch ^ ((px >> 2) & 1);
            const ushort_t* src = xn + (((size_t)(img * 128 + h)) * 8 + p) * 2048
                                  + px * 16 + cg * 8;
            async16(src, (char*)lds + b * 4096 + kb * 1024);
        }
    };

    STAGE(0, 0);
    STAGE(1, 1);
    #pragma unroll
    for (int p = 0; p < 8; ++p) {
        const int fbase = p * 4 + coh * 2;
        bf16x8 wa0 = *(const bf16x8*)(Wb + ((size_t)fbase * 64 + lane) * 8);
        bf16x8 wa1 = *(const bf16x8*)(Wb + ((size_t)(fbase + 1) * 64 + lane) * 8);
        asm volatile("" ::: "memory");
        if (p < 6) STAGE(p + 2, (p + 2) % 3);
        if (p < 6)      asm volatile("s_waitcnt vmcnt(4)" ::: "memory");
        else if (p == 6) asm volatile("s_waitcnt vmcnt(3)" ::: "memory");
        else             asm volatile("s_waitcnt vmcnt(2)" ::: "memory");
        __builtin_amdgcn_s_barrier();
        __builtin_amdgcn_s_setprio(1);
        const ushort_t* bbuf = lds + (p % 3) * 2048;
        #pragma unroll
        for (int i = 0; i < 2; ++i) {
            int px = pxh * 64 + i * 32 + (lane & 31);
            int s = kch ^ ((px >> 2) & 1);
            bf16x8 bv4 = *(const bf16x8*)(bbuf + px * 16 + s * 8);
            acc[i][0] = __builtin_amdgcn_mfma_f32_32x32x16_bf16(wa0, bv4, acc[i][0], 0, 0, 0);
            acc[i][1] = __builtin_amdgcn_mfma_f32_32x32x16_bf16(wa1, bv4, acc[i][1], 0, 0, 0);
        }
        __builtin_amdgcn_s_setprio(0);
        __builtin_amdgcn_s_barrier();
    }

    // ---- coalesced windowed epilogue (per j: deposit to LDS, write uint4 runs)
    #pragma unroll
    for (int j = 0; j < 2; ++j) {
        __syncthreads();   // staging/previous-tile reads complete
        {
            const int scale = coh * 2 + j;
            ushort_t* tile = lds + w3 * 8192 + coh * 4096;   // [c_local][128 px]
            #pragma unroll
            for (int rg = 0; rg < 16; ++rg) {
                int c_local = (rg & 3) + 8 * (rg >> 2) + 4 * kch;
                float bb = bias[scale * 32 + c_local];
                #pragma unroll
                for (int i = 0; i < 2; ++i) {
                    int px = pxh * 64 + i * 32 + (lane & 31);
                    tile[c_local * 128 + px] = (ushort_t)f2bf(acc[i][j][rg] + bb);
                }
            }
        }
        __syncthreads();
        // 3072 uint4 runs (3 w3 x 2 coh x 512) over 768 threads
        #pragma unroll
        for (int l = 0; l < 4; ++l) {
            int idx = l * 768 + tid;                 // 0..3071
            int g3 = idx >> 10, rem = idx & 1023;
            int coh_t = rem >> 9, rem2 = rem & 511;
            int c_local = rem2 >> 4, r8 = rem2 & 15;
            int px0 = r8 * 8;
            int scale = coh_t * 2 + j;
            int lg = 6 - scale;
            int psz = 1 << lg, outn = 128 >> lg;
            int Dd = 32 << (2 * lg);
            int oh = h >> lg, ph = h & (psz - 1);
            int ow = px0 >> lg, pw0 = px0 & (psz - 1);
            ushort_t* outp = (g3 == 0) ? qw : ((g3 == 1) ? kw : vw);
            size_t off = (size_t)scale * 8388608u
                + ((size_t)((b_ * 4 + t_) * outn * outn + oh * outn)) * (size_t)Dd
                + (size_t)ow * Dd + (size_t)(((c_local << lg) + ph) << lg) + pw0;
            uint4 raw = *(const uint4*)&lds[g3 * 8192 + coh_t * 4096 + c_local * 128 + px0];
            *(uint4*)&outp[off] = raw;
        }
    }
}

// ---------------------------------------------------------------------------
// V transpose, all scales fused (unchanged). grid 6144.
// ---------------------------------------------------------------------------
__device__ __forceinline__ void vtrans_dev(
    const ushort_t* __restrict__ src, ushort_t* __restrict__ dst,
    int n, int Dd, int xb, int yb, int b_)
{
    const int ddb = xb * 128, tokb = yb * 128;
    const int tid = threadIdx.x;
    const int ti = tid & 15, tj = tid >> 4;
    const int tok0 = tokb + ti * 8, dd0 = ddb + tj * 8;
    if (tok0 >= n) return;
    const ushort_t* s = src + (size_t)b_ * (size_t)n * Dd;
    ushort_t* d = dst + (size_t)b_ * (size_t)n * Dd;
    ushort_t a[8][8];
    #pragma unroll
    for (int e = 0; e < 8; ++e)
        *(uint4*)a[e] = *(const uint4*)&s[(size_t)(tok0 + e) * Dd + dd0];
    #pragma unroll
    for (int q = 0; q < 8; ++q) {
        ushort_t o[8];
        #pragma unroll
        for (int e = 0; e < 8; ++e) o[e] = a[e][q];
        *(uint4*)&d[(size_t)(dd0 + q) * n + tok0] = *(uint4*)o;
    }
}

__global__ __launch_bounds__(256) void vtrans_all_kernel(
    const ushort_t* __restrict__ vw, ushort_t* __restrict__ vt)
{
    const int bid = blockIdx.x;
    if (bid < 4096) {
        int sid = bid;
        vtrans_dev(vw + 0u, vt + 0u, 16, 131072, sid & 1023, 0, sid >> 10);
    } else if (bid < 5120) {
        int sid = bid - 4096;
        vtrans_dev(vw + 8388608u, vt + 8388608u, 64, 32768, sid & 255, 0, sid >> 8);
    } else if (bid < 5632) {
        int sid = bid - 5120;
        vtrans_dev(vw + 16777216u, vt + 16777216u, 256, 8192, sid & 63, (sid >> 6) & 1, sid >> 7);
    } else {
        int sid = bid - 5632;
        vtrans_dev(vw + 25165824u, vt + 25165824u, 1024, 2048, sid & 15, (sid >> 4) & 7, sid >> 7);
    }
}

// ---------------------------------------------------------------------------
// scores, LDS-tiled (s3, s2): 128x128 tile, BK=64 double-buffered,
// involution chunk-XOR swizzle, counted vmcnt, 4 waves share tiles.
// ---------------------------------------------------------------------------
template<int LG, int KS>
__device__ __forceinline__ void scores_lds_dev(
    const ushort_t* __restrict__ qw, const ushort_t* __restrict__ kw,
    float* __restrict__ sc_s, int bx, int by, int b_, int ks, ushort_t* lds)
{
    constexpr int outn = 128 >> LG;
    constexpr int n = 4 * outn * outn;
    constexpr int Dd = 32 << (2 * LG);
    constexpr int scale = 6 - LG;
    constexpr int DdK = Dd / KS;
    constexpr int NPH = DdK / 64;
    const size_t base = (size_t)scale * 8388608u;
    const int tid = threadIdx.x, lane = tid & 63, wv = tid >> 6;
    const ushort_t* qb = qw + base + (size_t)b_ * (size_t)n * Dd;
    const ushort_t* kb = kw + base + (size_t)b_ * (size_t)n * Dd;
    float* scb = sc_s + (size_t)b_ * n * n;
    const float scl = rsqrtf((float)Dd);
    const int mb = bx * 128, nb = by * 128;
    const int mbl = (wv & 1) * 64, nbl = (wv >> 1) * 64;
    const int k0beg = ks * DdK;

    f32x16 acc[2][2];
    #pragma unroll
    for (int i = 0; i < 2; ++i)
        #pragma unroll
        for (int j = 0; j < 2; ++j)
            #pragma unroll
            for (int k = 0; k < 16; ++k) acc[i][j][k] = 0.f;

    auto STAGE = [&](int k0, int buf) {
        #pragma unroll
        for (int l = 0; l < 4; ++l) {
            int id = l * 256 + tid;
            int row = id >> 3, ch = id & 7;
            int sw = ch ^ (row & 7);
            async16(qb + (size_t)(mb + row) * Dd + k0 + sw * 8,
                    (char*)lds + buf * 32768 + id * 16);
        }
        #pragma unroll
        for (int l = 0; l < 4; ++l) {
            int id = l * 256 + tid;
            int row = id >> 3, ch = id & 7;
            int sw = ch ^ (row & 7);
            async16(kb + (size_t)(nb + row) * Dd + k0 + sw * 8,
                    (char*)lds + buf * 32768 + 16384 + id * 16);
        }
    };

    STAGE(k0beg, 0);
    for (int p = 0; p < NPH; ++p) {
        if (p + 1 < NPH) STAGE(k0beg + (p + 1) * 64, (p + 1) & 1);
        if (p + 1 < NPH) asm volatile("s_waitcnt vmcnt(8)" ::: "memory");
        else             asm volatile("s_waitcnt vmcnt(0)" ::: "memory");
        __builtin_amdgcn_s_barrier();
        __builtin_amdgcn_s_setprio(1);
        const ushort_t* bufA = lds + (p & 1) * 16384;
        const ushort_t* bufB = bufA + 8192;
        #pragma unroll
        for (int u = 0; u < 4; ++u) {
            const int c = u * 2 + (lane >> 5);
            bf16x8 a[2], b[2];
            #pragma unroll
            for (int i = 0; i < 2; ++i) {
                int row = mbl + i * 32 + (lane & 31);
                a[i] = *(const bf16x8*)(bufA + row * 64 + ((c ^ (row & 7)) << 3));
            }
            #pragma unroll
            for (int j = 0; j < 2; ++j) {
                int row = nbl + j * 32 + (lane & 31);
                b[j] = *(const bf16x8*)(bufB + row * 64 + ((c ^ (row & 7)) << 3));
            }
            #pragma unroll
            for (int i = 0; i < 2; ++i)
                #pragma unroll
                for (int j = 0; j < 2; ++j)
                    acc[i][j] = __builtin_amdgcn_mfma_f32_32x32x16_bf16(a[i], b[j], acc[i][j], 0, 0, 0);
        }
        __builtin_amdgcn_s_setprio(0);
        __builtin_amdgcn_s_barrier();
    }

    #pragma unroll
    for (int i = 0; i < 2; ++i)
        #pragma unroll
        for (int j = 0; j < 2; ++j)
            #pragma unroll
            for (int rg = 0; rg < 16; ++rg) {
                int row = mb + mbl + i * 32 + (rg & 3) + 8 * (rg >> 2) + 4 * (lane >> 5);
                int col = nb + nbl + j * 32 + (lane & 31);
                float v = acc[i][j][rg] * scl;
                size_t off = (size_t)row * n + col;
                if (KS == 1) scb[off] = v;
                else atomicAdd(&scb[off], v);
            }
}

// ---------------------------------------------------------------------------
// scores direct body (s1 CFG1, s0 CFG2).
// ---------------------------------------------------------------------------
template<int CFG, int LG, int KS>
__device__ __forceinline__ void scores_dev(
    const ushort_t* __restrict__ qw, const ushort_t* __restrict__ kw,
    float* __restrict__ sc_s, int b_, int ks)
{
    constexpr int outn = 128 >> LG;
    constexpr int n = 4 * outn * outn;
    constexpr int Dd = 32 << (2 * LG);
    constexpr int scale = 6 - LG;
    constexpr int DdK = Dd / KS;
    const size_t base = (size_t)scale * 8388608u;
    const int tid = threadIdx.x, lane = tid & 63, wv = tid >> 6;
    const ushort_t* qb = qw + base + (size_t)b_ * (size_t)n * Dd;
    const ushort_t* kb = kw + base + (size_t)b_ * (size_t)n * Dd;
    float* scb = sc_s + (size_t)b_ * n * n;
    const float scl = rsqrtf((float)Dd);
    const int koff = (lane >> 5) * 8;
    const int mbq = (CFG == 1) ? (wv & 1) * 32 : 0;
    const int nbq = (CFG == 1) ? (wv >> 1) * 32 : 0;

    f32x16 acc;
    #pragma unroll
    for (int k = 0; k < 16; ++k) acc[k] = 0.f;

    int mrow = mbq + (lane & 31);
    int nrow = nbq + (lane & 31);
    if (CFG == 2) { if (mrow >= n) mrow = n - 1; if (nrow >= n) nrow = n - 1; }
    int k0beg = ks * DdK, k0end = k0beg + DdK;
    if (CFG == 2) { constexpr int DdW = DdK >> 2; k0beg += wv * DdW; k0end = k0beg + DdW; }

    for (int k0 = k0beg; k0 < k0end; k0 += 64) {
        bf16x8 a[4], b[4];
        #pragma unroll
        for (int u = 0; u < 4; ++u) {
            a[u] = *(const bf16x8*)(qb + (size_t)mrow * Dd + k0 + u * 16 + koff);
            b[u] = *(const bf16x8*)(kb + (size_t)nrow * Dd + k0 + u * 16 + koff);
        }
        #pragma unroll
        for (int u = 0; u < 4; ++u)
            acc = __builtin_amdgcn_mfma_f32_32x32x16_bf16(a[u], b[u], acc, 0, 0, 0);
    }

    #pragma unroll
    for (int rg = 0; rg < 16; ++rg) {
        int row = mbq + (rg & 3) + 8 * (rg >> 2) + 4 * (lane >> 5);
        int col = nbq + (lane & 31);
        if (CFG == 2 && (row >= n || col >= n)) continue;
        float v = acc[rg] * scl;
        size_t off = (size_t)row * n + col;
        atomicAdd(&scb[off], v);
    }
}

// fused: 1024 blocks, heavy s3 first, per-segment XCD swizzle
__global__ __launch_bounds__(256, 2) void scores_all_kernel(
    const ushort_t* __restrict__ qw, const ushort_t* __restrict__ kw,
    float* __restrict__ sc)
{
    __shared__ ushort_t slds[32768];   // 64 KB: 2 bufs x (A 16KB + B 16KB)
    const int bid = blockIdx.x;
    if (bid < 256) {                 // s3: 8x8x4, KS=1
        int l = bid;            int sid = (l & 7) * 32 + (l >> 3);
        scores_lds_dev<3, 1>(qw, kw, sc + SC_OFF3, sid & 7, (sid >> 3) & 7, sid >> 6, 0, slds);
    } else if (bid < 512) {          // s2: 2x2x4x16ks
        int l = bid - 256;      int sid = (l & 7) * 32 + (l >> 3);
        scores_lds_dev<4, 16>(qw, kw, sc + SC_OFF2, sid & 1, (sid >> 1) & 1, sid >> 6, (sid >> 2) & 15, slds);
    } else if (bid < 768) {          // s1: 4x64ks
        int l = bid - 512;      int sid = (l & 7) * 32 + (l >> 3);
        scores_dev<1, 5, 64>(qw, kw, sc + SC_OFF1, sid >> 6, sid & 63);
    } else {                         // s0: 4x64ks
        int l = bid - 768;      int sid = (l & 7) * 32 + (l >> 3);
        scores_dev<2, 6, 64>(qw, kw, sc + SC_OFF0, sid >> 6, sid & 63);
    }
}

// ---------------------------------------------------------------------------
// softmax fused over all scales (unchanged). grid 5440.
// ---------------------------------------------------------------------------
__global__ __launch_bounds__(256) void softmax_all_kernel(
    const float* __restrict__ sc, ushort_t* __restrict__ pbf)
{
    const int bid = blockIdx.x;
    int n; size_t off; int row;
    if (bid < 64)        { n = 16;   row = bid;        off = SC_OFF0; }
    else if (bid < 320)  { n = 64;   row = bid - 64;   off = SC_OFF1; }
    else if (bid < 1344) { n = 256;  row = bid - 320;  off = SC_OFF2; }
    else                 { n = 1024; row = bid - 1344; off = SC_OFF3; }
    const float* p = sc + off + (size_t)row * n;
    ushort_t* q = pbf + off + (size_t)row * n;
    const int tid = threadIdx.x;
    float v[4];
    #pragma unroll
    for (int j = 0; j < 4; ++j) { int idx = tid + 256 * j; v[j] = (idx < n) ? p[idx] : -3.0e38f; }
    float m = fmaxf(fmaxf(v[0], v[1]), fmaxf(v[2], v[3]));
    #pragma unroll
    for (int off2 = 32; off2 >= 1; off2 >>= 1) m = fmaxf(m, __shfl_xor(m, off2));
    __shared__ float red[4];
    const int wid = tid >> 6, lane = tid & 63;
    if (lane == 0) red[wid] = m;
    __syncthreads();
    m = fmaxf(fmaxf(red[0], red[1]), fmaxf(red[2], red[3]));
    float e[4]; float s = 0.f;
    #pragma unroll
    for (int j = 0; j < 4; ++j) { int idx = tid + 256 * j; e[j] = (idx < n) ? __expf(v[j] - m) : 0.f; s += e[j]; }
    #pragma unroll
    for (int off2 = 32; off2 >= 1; off2 >>= 1) s += __shfl_xor(s, off2);
    __syncthreads();
    if (lane == 0) red[wid] = s;
    __syncthreads();
    s = red[0] + red[1] + red[2] + red[3];
    float inv = 1.0f / s;
    #pragma unroll
    for (int j = 0; j < 4; ++j) {
        int idx = tid + 256 * j;
        if (idx < n) q[idx] = (ushort_t)f2bf(e[j] * inv);
    }
}

// ---------------------------------------------------------------------------
// PV, LDS-tiled (s3, s2): P-tile (tok x k) + V^T-tile (dd x k) staged via
// involution swizzle, double-buffered 64-k phases, counted vmcnt.
// ---------------------------------------------------------------------------
template<int LG>
__device__ __forceinline__ void pvm_lds_dev(
    const ushort_t* __restrict__ pbf_s, const ushort_t* __restrict__ vt,
    ushort_t* __restrict__ attn, int bx, int by, int b_, ushort_t* lds)
{
    constexpr int outn = 128 >> LG, psz = 1 << LG;
    constexpr int n = 4 * outn * outn;
    constexpr int Dd = 32 << (2 * LG);
    constexpr int scale = 6 - LG;
    constexpr int NPH = n / 64;
    const int tid = threadIdx.x, lane = tid & 63, wv = tid >> 6;
    const ushort_t* pb = pbf_s + (size_t)b_ * n * n;
    const ushort_t* vb = vt + (size_t)scale * 8388608u + (size_t)b_ * (size_t)Dd * n;
    const int mb = by * 128;        // tok base
    const int nb = bx * 128;        // dd base
    const int mbl = (wv & 1) * 64, nbl = (wv >> 1) * 64;

    f32x16 acc[2][2];
    #pragma unroll
    for (int i = 0; i < 2; ++i)
        #pragma unroll
        for (int j = 0; j < 2; ++j)
            #pragma unroll
            for (int k = 0; k < 16; ++k) acc[i][j][k] = 0.f;

    auto STAGE = [&](int k0, int buf) {
        #pragma unroll
        for (int l = 0; l < 4; ++l) {
            int id = l * 256 + tid;
            int row = id >> 3, ch = id & 7;
            int sw = ch ^ (row & 7);
            async16(pb + (size_t)(mb + row) * n + k0 + sw * 8,
                    (char*)lds + buf * 32768 + id * 16);
        }
        #pragma unroll
        for (int l = 0; l < 4; ++l) {
            int id = l * 256 + tid;
            int row = id >> 3, ch = id & 7;
            int sw = ch ^ (row & 7);
            async16(vb + (size_t)(nb + row) * n + k0 + sw * 8,
                    (char*)lds + buf * 32768 + 16384 + id * 16);
        }
    };

    STAGE(0, 0);
    for (int p = 0; p < NPH; ++p) {
        if (p + 1 < NPH) STAGE((p + 1) * 64, (p + 1) & 1);
        if (p + 1 < NPH) asm volatile("s_waitcnt vmcnt(8)" ::: "memory");
        else             asm volatile("s_waitcnt vmcnt(0)" ::: "memory");
        __builtin_amdgcn_s_barrier();
        __builtin_amdgcn_s_setprio(1);
        const ushort_t* bufA = lds + (p & 1) * 16384;
        const ushort_t* bufB = bufA + 8192;
        #pragma unroll
        for (int u = 0; u < 4; ++u) {
            const int c = u * 2 + (lane >> 5);
            bf16x8 a[2], b[2];
            #pragma unroll
            for (int i = 0; i < 2; ++i) {
                int row = mbl + i * 32 + (lane & 31);
                a[i] = *(const bf16x8*)(bufA + row * 64 + ((c ^ (row & 7)) << 3));
            }
            #pragma unroll
            for (int j = 0; j < 2; ++j) {
                int row = nbl + j * 32 + (lane & 31);
                b[j] = *(const bf16x8*)(bufB + row * 64 + ((c ^ (row & 7)) << 3));
            }
            #pragma unroll
            for (int i = 0; i < 2; ++i)
                #pragma unroll
                for (int j = 0; j < 2; ++j)
                    acc[i][j] = __builtin_amdgcn_mfma_f32_32x32x16_bf16(a[i], b[j], acc[i][j], 0, 0, 0);
        }
        __builtin_amdgcn_s_setprio(0);
        __builtin_amdgcn_s_barrier();
    }

    constexpr int lgo = 7 - LG;
    #pragma unroll
    for (int i = 0; i < 2; ++i)
        #pragma unroll
        for (int j = 0; j < 2; ++j)
            #pragma unroll
            for (int rg = 0; rg < 16; ++rg) {
                int tok = mb + mbl + i * 32 + (rg & 3) + 8 * (rg >> 2) + 4 * (lane >> 5);
                int dd = nb + nbl + j * 32 + (lane & 31);
                int c_local = dd >> (2 * LG);
                int p2 = dd & (psz * psz - 1);
                int ph = p2 >> LG, pw = p2 & (psz - 1);
                int t_ = tok >> (2 * lgo);
                int rem = tok & ((1 << (2 * lgo)) - 1);
                int oh = rem >> lgo, ow = rem & (outn - 1);
                size_t off = (((size_t)(scale * 16 + b_ * 4 + t_) * 32 + c_local) * 128
                              + ((oh << LG) + ph)) * 128 + ((ow << LG) + pw);
                attn[off] = (ushort_t)f2bf(acc[i][j][rg]);
            }
}

// ---------------------------------------------------------------------------
// PV direct body (s1 CFG1, s0 CFG2).
// ---------------------------------------------------------------------------
template<int CFG, int LG>
__device__ __forceinline__ void pvm_dev(
    const ushort_t* __restrict__ pbf_s, const ushort_t* __restrict__ vt,
    ushort_t* __restrict__ attn, int bx, int by, int b_)
{
    constexpr int outn = 128 >> LG, psz = 1 << LG;
    constexpr int n = 4 * outn * outn;
    constexpr int Dd = 32 << (2 * LG);
    constexpr int scale = 6 - LG;
    const int tid = threadIdx.x, lane = tid & 63, wv = tid >> 6;
    const ushort_t* pb = pbf_s + (size_t)b_ * n * n;
    const ushort_t* vb = vt + (size_t)scale * 8388608u + (size_t)b_ * (size_t)Dd * n;
    const int mb = (CFG == 1) ? (wv & 1) * 32 : 0;
    const int nb = (CFG == 1) ? bx * 128 + (wv >> 1) * 64
                              : bx * 256 + wv * 64;
    const int koff = (lane >> 5) * 8;

    f32x16 acc[2];
    #pragma unroll
    for (int j = 0; j < 2; ++j)
        #pragma unroll
        for (int k = 0; k < 16; ++k) acc[j][k] = 0.f;

    int mr = mb + (lane & 31);
    if (CFG == 2 && mr >= n) mr = n - 1;
    const int nr0 = nb + (lane & 31), nr1 = nr0 + 32;

    if constexpr (CFG == 2) {
        bf16x8 b0 = *(const bf16x8*)(vb + (size_t)nr0 * n + koff);
        bf16x8 b1 = *(const bf16x8*)(vb + (size_t)nr1 * n + koff);
        bf16x8 a = *(const bf16x8*)(pb + (size_t)mr * n + koff);
        acc[0] = __builtin_amdgcn_mfma_f32_32x32x16_bf16(a, b0, acc[0], 0, 0, 0);
        acc[1] = __builtin_amdgcn_mfma_f32_32x32x16_bf16(a, b1, acc[1], 0, 0, 0);
    } else {
        for (int k0 = 0; k0 < n; k0 += 64) {
            bf16x8 vb0[4], vb1[4], pa[4];
            #pragma unroll
            for (int u = 0; u < 4; ++u) {
                vb0[u] = *(const bf16x8*)(vb + (size_t)nr0 * n + k0 + u * 16 + koff);
                vb1[u] = *(const bf16x8*)(vb + (size_t)nr1 * n + k0 + u * 16 + koff);
                pa[u]  = *(const bf16x8*)(pb + (size_t)mr * n + k0 + u * 16 + koff);
            }
            #pragma unroll
            for (int u = 0; u < 4; ++u) {
                acc[0] = __builtin_amdgcn_mfma_f32_32x32x16_bf16(pa[u], vb0[u], acc[0], 0, 0, 0);
                acc[1] = __builtin_amdgcn_mfma_f32_32x32x16_bf16(pa[u], vb1[u], acc[1], 0, 0, 0);
            }
        }
    }

    constexpr int lgo = 7 - LG;
    #pragma unroll
    for (int j = 0; j < 2; ++j)
        #pragma unroll
        for (int rg = 0; rg < 16; ++rg) {
            int tok = mb + (rg & 3) + 8 * (rg >> 2) + 4 * (lane >> 5);
            if (CFG == 2 && tok >= n) continue;
            int dd = nb + j * 32 + (lane & 31);
            int c_local = dd >> (2 * LG);
            int p2 = dd & (psz * psz - 1);
            int ph = p2 >> LG, pw = p2 & (psz - 1);
            int t_ = tok >> (2 * lgo);
            int rem = tok & ((1 << (2 * lgo)) - 1);
            int oh = rem >> lgo, ow = rem & (outn - 1);
            size_t off = (((size_t)(scale * 16 + b_ * 4 + t_) * 32 + c_local) * 128
                          + ((oh << LG) + ph)) * 128 + ((ow << LG) + pw);
            attn[off] = (ushort_t)f2bf(acc[j][rg]);
        }
}

// fused: 4096 blocks, heavy s3 first, per-segment XCD swizzle
__global__ __launch_bounds__(256, 2) void pvm_all_kernel(
    const ushort_t* __restrict__ pbf, const ushort_t* __restrict__ vt,
    ushort_t* __restrict__ attn)
{
    __shared__ ushort_t plds[32768];   // 64 KB: 2 bufs x (P 16KB + V 16KB)
    const int bid = blockIdx.x;
    if (bid < 512) {                 // s3: 16x8x4 (LDS-tiled)
        int l = bid;            int sid = (l & 7) * 64 + (l >> 3);
        pvm_lds_dev<3>(pbf + SC_OFF3, vt, attn, sid & 15, (sid >> 4) & 7, sid >> 7, plds);
    } else if (bid < 1024) {         // s2: 64x2x4 (LDS-tiled)
        int l = bid - 512;      int sid = (l & 7) * 64 + (l >> 3);
        pvm_lds_dev<4>(pbf + SC_OFF2, vt, attn, sid & 63, (sid >> 6) & 1, sid >> 7, plds);
    } else if (bid < 2048) {         // s1: 256x4
        int l = bid - 1024;     int sid = (l & 7) * 128 + (l >> 3);
        pvm_dev<1, 5>(pbf + SC_OFF1, vt, attn, sid & 255, 0, sid >> 8);
    } else {                         // s0: 512x4
        int l = bid - 2048;     int sid = (l & 7) * 256 + (l >> 3);
        pvm_dev<2, 6>(pbf + SC_OFF0, vt, attn, sid & 511, 0, sid >> 9);
    }
}

// ---------------------------------------------------------------------------
// MFMA implicit-GEMM 3x3 conv v5 (unchanged from r12).
// ---------------------------------------------------------------------------
template<int DIL, int MODE>
__global__ __launch_bounds__(256, 2) void conv3x_kernel(
    const ushort_t* __restrict__ in, const ushort_t* __restrict__ Wp,
    const float* __restrict__ bias, const ushort_t* __restrict__ resn,
    float* __restrict__ outf, ushort_t* __restrict__ outn,
    const ushort_t* __restrict__ zp)
{
    __shared__ ushort_t lds[34816];
    const int fid = blockIdx.y * 64 + blockIdx.x;        // 0..1023
    const int nfid = (fid & 7) * 128 + (fid >> 3);       // XCD-bijective
    const int img = nfid >> 6, rp = nfid & 63;
    const int h0 = (DIL == 1) ? rp * 2 : ((rp & 1) + (rp >> 1) * 4);
    const int tid = threadIdx.x, lane = tid & 63, wv = tid >> 6;
    const int pxh = wv & 1, coq = wv >> 1;
    const int kch = lane >> 5;

    f32x16 acc[2][2][2];   // [row][i(px)][tn]
    #pragma unroll
    for (int r = 0; r < 2; ++r)
        #pragma unroll
        for (int i = 0; i < 2; ++i)
            #pragma unroll
            for (int j = 0; j < 2; ++j)
                #pragma unroll
                for (int k = 0; k < 16; ++k) acc[r][i][j][k] = 0.f;

    auto STAGE = [&](int p, int b) {
        #pragma unroll
        for (int kb = wv; kb < 20; kb += 4) {      // 5 loads per wave
            int slot = kb / 5, pg = kb % 5;
            int pxi = pg * 32 + (lane >> 1);
            int wc = pxi - 16;
            int ir = h0 - DIL + slot * DIL;
            int cg = (lane & 1) ^ ((pxi >> 2) & 1);
            const ushort_t* src;
            if (wc >= 0 && wc < 128 && ir >= 0 && ir < 128)
                src = in + (((size_t)(img * 128 + ir)) * 8 + p) * 2048 + wc * 16 + cg * 8;
            else
                src = zp + lane * 8;
            async16(src, (char*)lds + b * 20480 + kb * 1024);
        }
    };

    STAGE(0, 0);
    #pragma unroll
    for (int p = 0; p < 8; ++p) {
        bf16x8 w0[9], w1[9];
        #pragma unroll
        for (int tap = 0; tap < 9; ++tap) {
            int fbase = (((p >> 1) * 9 + tap) * 2 + (p & 1)) * 4 + coq * 2;
            w0[tap] = *(const bf16x8*)(Wp + ((size_t)fbase * 64 + lane) * 8);
            w1[tap] = *(const bf16x8*)(Wp + ((size_t)(fbase + 1) * 64 + lane) * 8);
        }
        asm volatile("" ::: "memory");
        if (p < 7) STAGE(p + 1, (p + 1) & 1);
        if (p < 7) asm volatile("s_waitcnt vmcnt(23)" ::: "memory");
        else       asm volatile("s_waitcnt vmcnt(18)" ::: "memory");
        __builtin_amdgcn_s_barrier();
        __builtin_amdgcn_s_setprio(1);
        const ushort_t* bbuf = lds + (p & 1) * 10240;
        #pragma unroll
        for (int tap = 0; tap < 9; ++tap) {
            const int tr = tap / 3, tc = tap % 3;
            #pragma unroll
            for (int r = 0; r < 2; ++r) {
                const ushort_t* sb = bbuf + (r + tr) * 2560;
                #pragma unroll
                for (int i = 0; i < 2; ++i) {
                    int pxi = pxh * 64 + i * 32 + (lane & 31) + (tc - 1) * DIL + 16;
                    int s = kch ^ ((pxi >> 2) & 1);
                    bf16x8 bv = *(const bf16x8*)(sb + pxi * 16 + s * 8);
                    acc[r][i][0] = __builtin_amdgcn_mfma_f32_32x32x16_bf16(w0[tap], bv, acc[r][i][0], 0, 0, 0);
                    acc[r][i][1] = __builtin_amdgcn_mfma_f32_32x32x16_bf16(w1[tap], bv, acc[r][i][1], 0, 0, 0);
                }
            }
        }
        __builtin_amdgcn_s_setprio(0);
        __builtin_amdgcn_s_barrier();
    }
    __syncthreads();

    if (MODE == 0 || MODE == 2) {
        #pragma unroll
        for (int r = 0; r < 2; ++r) {
            const int hr = h0 + r * DIL;
            for (int u = tid; u < 2048; u += 256) {
                int px = u >> 4, c8 = (u & 15) * 8;
                size_t soff = (((size_t)(img * 128 + hr)) * 8 + (c8 >> 4)) * 2048 + px * 16 + (c8 & 8);
                *(uint4*)&lds[r * 17408 + px * 136 + c8] = *(const uint4*)&resn[soff];
            }
        }
        __syncthreads();
    }
    #pragma unroll
    for (int r = 0; r < 2; ++r) {
        const int hr = h0 + r * DIL;
        #pragma unroll
        for (int i = 0; i < 2; ++i)
            #pragma unroll
            for (int tn = 0; tn < 2; ++tn)
                #pragma unroll
                for (int rgq = 0; rgq < 4; ++rgq) {
                    const int cob = coq * 64 + tn * 32 + 8 * rgq + 4 * kch;
                    const int px = pxh * 64 + i * 32 + (lane & 31);
                    float v[4];
                    #pragma unroll
                    for (int e = 0; e < 4; ++e) {
                        float t = acc[r][i][tn][rgq * 4 + e] + bias[cob + e];
                        v[e] = (t >= 0.f) ? t : 0.2f * t;
                    }
                    if (MODE == 0) {
                        uint2 rr = *(const uint2*)&lds[r * 17408 + px * 136 + cob];
                        float w0v = bf2f(rr.x & 0xffffu) + v[0];
                        float w1v = bf2f(rr.x >> 16)     + v[1];
                        float w2v = bf2f(rr.y & 0xffffu) + v[2];
                        float w3v = bf2f(rr.y >> 16)     + v[3];
                        uint2 pk;
                        pk.x = f2bf(w0v) | (f2bf(w1v) << 16);
                        pk.y = f2bf(w2v) | (f2bf(w3v) << 16);
                        *(uint2*)&lds[r * 17408 + px * 136 + cob] = pk;
                    } else if (MODE == 1) {
                        uint2 pk;
                        pk.x = f2bf(v[0]) | (f2bf(v[1]) << 16);
                        pk.y = f2bf(v[2]) | (f2bf(v[3]) << 16);
                        *(uint2*)&lds[r * 17408 + px * 136 + cob] = pk;
                    } else {
                        uint2 rr = *(const uint2*)&lds[r * 17408 + px * 136 + cob];
                        float rv[4] = { bf2f(rr.x & 0xffffu), bf2f(rr.x >> 16),
                                        bf2f(rr.y & 0xffffu), bf2f(rr.y >> 16) };
                        #pragma unroll
                        for (int e = 0; e < 4; ++e)
                            outf[(((size_t)(img * 128 + cob + e)) * 128 + hr) * 128 + px] = rv[e] + v[e];
                    }
                }
    }
    if (MODE == 0 || MODE == 1) {
        __syncthreads();
        #pragma unroll
        for (int r = 0; r < 2; ++r) {
            const int hr = h0 + r * DIL;
            for (int u = tid; u < 2048; u += 256) {
                int px = u >> 4, c8 = (u & 15) * 8;
                size_t doff = (((size_t)(img * 128 + hr)) * 8 + (c8 >> 4)) * 2048 + px * 16 + (c8 & 8);
                *(uint4*)&outn[doff] = *(const uint4*)&lds[r * 17408 + px * 136 + c8];
            }
        }
    }
}

// ---------------------------------------------------------------------------
extern "C" void kernel_launch(void* const* d_in, const int* in_sizes, int n_in,
                              void* d_out, int out_size, void* d_ws, size_t ws_size,
                              hipStream_t stream)
{
    const float* x   = (const float*)d_in[0];
    const float* Wq  = (const float*)d_in[1];
    const float* bq  = (const float*)d_in[2];
    const float* Wk  = (const float*)d_in[3];
    const float* bk  = (const float*)d_in[4];
    const float* Wv  = (const float*)d_in[5];
    const float* bv  = (const float*)d_in[6];
    const float* Wo  = (const float*)d_in[7];
    const float* bo  = (const float*)d_in[8];
    const float* Wf1 = (const float*)d_in[9];
    const float* bf1 = (const float*)d_in[10];
    const float* Wf2 = (const float*)d_in[11];
    const float* bf2 = (const float*)d_in[12];
    float* out = (float*)d_out;
    char* ws = (char*)d_ws;
    const size_t MB = 1048576ull;
    ushort_t* qw   = (ushort_t*)(ws);                 // 64 MB; attnc alias; later ff1n
    ushort_t* kw   = (ushort_t*)(ws + 64 * MB);       // 64 MB; later vt; later x1n
    ushort_t* vw   = (ushort_t*)(ws + 128 * MB);      // 64 MB; later attn NHWC-p
    ushort_t* xn   = (ushort_t*)(ws + 192 * MB);      // 64 MB; x NHWC-p (lives to conv1)
    float*    sc   = (float*)   (ws + 256 * MB);      // 17.9 MB
    ushort_t* Wp   = (ushort_t*)(ws + 274 * MB);      // 864 KB
    ushort_t* Wqkv = (ushort_t*)(ws + 275 * MB);      // 96 KB
    ushort_t* zp   = (ushort_t*)(ws + 275 * MB + 256 * 1024);  // 1 KB zeros
    ushort_t* pbf  = (ushort_t*)(ws + 276 * MB);      // 8.95 MB
    ushort_t* attnc = qw;    // attn scale-chunk NCHW (qw dead after scores)
    ushort_t* vt    = kw;    // V^T all scales (kw dead after scores)
    ushort_t* nhwc  = vw;    // attn NHWC-p (vw dead after vtrans)
    ushort_t* x1n   = kw;    // x1 NHWC-p (vt dead after pvm)
    ushort_t* ff1n  = qw;    // ff1 NHWC-p (attnc dead after attn2nhwc)

    hipMemsetAsync(zp, 0, 1024, stream);
    hipMemsetAsync(sc + SC_OFF2, 0, (size_t)(SC_TOT - SC_OFF2) * 4, stream);
    prepack_kernel<<<dim3(576, 3), 256, 0, stream>>>(Wo, Wf1, Wf2, Wp);
    prepack1_kernel<<<dim3(64, 3), 256, 0, stream>>>(Wq, Wk, Wv, Wqkv);

    // 1) x -> NHWC-p, then fused q/k/v (input staged once)
    nchw2nhwc_kernel<<<dim3(128, 16), 256, 0, stream>>>(x, xn);
    qkvm_kernel<<<dim3(128, 16), 768, 0, stream>>>(xn, Wqkv, bq, bk, bv, qw, kw, vw);

    // 2) attention
    scores_all_kernel<<<dim3(1024), 256, 0, stream>>>(qw, kw, sc);
    vtrans_all_kernel<<<dim3(6144), 256, 0, stream>>>(vw, vt);   // kw dead -> vt
    softmax_all_kernel<<<dim3(5440), 256, 0, stream>>>(sc, pbf);
    pvm_all_kernel<<<dim3(4096), 256, 0, stream>>>(pbf, vt, attnc);

    // 3) attn chunks -> NHWC-p (into vw region)
    attn2nhwc_kernel<<<dim3(128, 16), 256, 0, stream>>>(attnc, nhwc);
    // 4) x1 = x + lrelu(conv3x3(attn)) -> x1n NHWC-p (kw region)
    conv3x_kernel<1, 0><<<dim3(64, 16), 256, 0, stream>>>(nhwc, Wp, bo, xn, nullptr, x1n, zp);
    // 5) ff1 = lrelu(conv3x3 dil2(x1)) -> ff1n NHWC-p (qw region)
    conv3x_kernel<2, 1><<<dim3(64, 16), 256, 0, stream>>>(x1n, Wp + 147456, bf1, nullptr, nullptr, ff1n, zp);
    // 6) out = x1 + lrelu(conv3x3(ff1)) -> d_out fp32 NCHW
    conv3x_kernel<1, 2><<<dim3(64, 16), 256, 0, stream>>>(ff1n, Wp + 2 * 147456, bf2, x1n, out, nullptr, zp);
}

// Round 16
// 630.192 us; speedup vs baseline: 1.0581x; 1.0581x over previous
//
#include <hip/hip_runtime.h>
#include <stdint.h>

#define C_   128
#define H_   128
#define W_   128
#define HW_  (128*128)

// sc/pbf per-scale element offsets (s3 first, then s2, s1, s0)
#define SC_OFF3 0
#define SC_OFF2 4194304
#define SC_OFF1 4456448
#define SC_OFF0 4472832
#define SC_TOT  4473856

typedef unsigned short ushort_t;
typedef __attribute__((ext_vector_type(8)))  short bf16x8;
typedef __attribute__((ext_vector_type(16))) float f32x16;

__device__ __forceinline__ float bf2f(uint32_t u) {
    union { float f; uint32_t i; } v; v.i = u << 16; return v.f;
}
__device__ __forceinline__ uint32_t f2bf(float f) {
    union { float f; uint32_t i; } v; v.f = f;
    uint32_t u = v.i;
    uint32_t r = u + 0x7FFFu + ((u >> 16) & 1u);
    return r >> 16;  // RTNE bf16 bits in low 16
}
__device__ __forceinline__ void async16(const ushort_t* g, void* l) {
    __builtin_amdgcn_global_load_lds(
        (const __attribute__((address_space(1))) unsigned int*)g,
        (__attribute__((address_space(3))) unsigned int*)l, 16, 0, 0);
}

// NHWC-p layout: element (img, h, c, w) at ((img*128+h)*8 + (c>>4))*2048 + w*16 + (c&15)
// attn scale-chunk NCHW: ((scale*16+img)*32 + c_local)*16384 + h*128 + w (aliases qw)
// windowed layout per scale (PERMUTED dd): base = scale*8388608 +
//   (b*Ntok + tok)*Dd + dd', where dd' = ph*(32*psz) + c_local*psz + pw.
//   Legal because scores dot-products whole rows and pvm decodes dd'.
// V^T (vt, aliases kw): vt + scale*8388608 + (b*Dd + dd')*n + tok

// ---------------------------------------------------------------------------
// prepack conv weights -> MFMA A-fragment-linear order (bf16).
// ---------------------------------------------------------------------------
__global__ __launch_bounds__(256) void prepack_kernel(
    const float* __restrict__ Wo, const float* __restrict__ Wf1,
    const float* __restrict__ Wf2, ushort_t* __restrict__ Wp)
{
    int t = blockIdx.x * 256 + threadIdx.x;          // 0..147455
    const float* W = (blockIdx.y == 0) ? Wo : ((blockIdx.y == 1) ? Wf1 : Wf2);
    ushort_t* dst = Wp + (size_t)blockIdx.y * 147456;
    int j = t & 7, lane = (t >> 3) & 63, f = t >> 9;
    int cot = f & 3, s = (f >> 2) & 1, tap = (f >> 3) % 9, cc = f / 72;
    int co = cot * 32 + (lane & 31);
    int ci = cc * 32 + s * 16 + (lane >> 5) * 8 + j;
    dst[t] = (ushort_t)f2bf(W[((size_t)co * 128 + ci) * 9 + tap]);
}

// ---------------------------------------------------------------------------
// prepack 1x1 qkv weights -> A-fragment-linear (bf16). grid (64, 3).
// ---------------------------------------------------------------------------
__global__ __launch_bounds__(256) void prepack1_kernel(
    const float* __restrict__ Wq, const float* __restrict__ Wk,
    const float* __restrict__ Wv, ushort_t* __restrict__ Wqkv)
{
    int t = blockIdx.x * 256 + threadIdx.x;          // 0..16383
    const float* W = (blockIdx.y == 0) ? Wq : ((blockIdx.y == 1) ? Wk : Wv);
    ushort_t* dst = Wqkv + (size_t)blockIdx.y * 16384;
    int j = t & 7, lane = (t >> 3) & 63, f = t >> 9;  // f 0..31
    int cot = f & 3, s = f >> 2;
    int co = cot * 32 + (lane & 31);
    int ci = s * 16 + (lane >> 5) * 8 + j;
    dst[t] = (ushort_t)f2bf(W[(size_t)co * 128 + ci]);
}

// ---------------------------------------------------------------------------
// NCHW fp32 -> NHWC-p bf16 (for x). grid (128, 16).
// ---------------------------------------------------------------------------
__global__ __launch_bounds__(256) void nchw2nhwc_kernel(
    const float* __restrict__ in, ushort_t* __restrict__ out)
{
    __shared__ ushort_t tile[128 * 136];
    const int img = blockIdx.y, hh = blockIdx.x;
    const int tid = threadIdx.x;
    #pragma unroll
    for (int i = 0; i < 8; ++i) {
        int idx = tid + 256 * i;
        int c = idx >> 4, w8 = (idx & 15) * 8;
        size_t src = ((size_t)img * 128 + c) * (size_t)HW_ + hh * 128 + w8;
        const float4* fp = (const float4*)&in[src];
        float4 f0 = fp[0], f1 = fp[1];
        ushort_t v[8];
        v[0] = (ushort_t)f2bf(f0.x); v[1] = (ushort_t)f2bf(f0.y);
        v[2] = (ushort_t)f2bf(f0.z); v[3] = (ushort_t)f2bf(f0.w);
        v[4] = (ushort_t)f2bf(f1.x); v[5] = (ushort_t)f2bf(f1.y);
        v[6] = (ushort_t)f2bf(f1.z); v[7] = (ushort_t)f2bf(f1.w);
        #pragma unroll
        for (int k = 0; k < 8; ++k) {
            int w = w8 + k;
            int g = (c >> 3) ^ ((w >> 3) & 7);
            tile[w * 136 + g * 8 + (c & 7)] = v[k];
        }
    }
    __syncthreads();
    #pragma unroll
    for (int i = 0; i < 8; ++i) {
        int idx = tid + 256 * i;
        int w = idx >> 4, g = idx & 15;
        int gs = g ^ ((w >> 3) & 7);
        uint4 raw = *(const uint4*)&tile[w * 136 + gs * 8];
        int c8 = g * 8;
        size_t off = (((size_t)(img * 128 + hh)) * 8 + (c8 >> 4)) * 2048 + w * 16 + (c8 & 8);
        *(uint4*)&out[off] = raw;
    }
}

// ---------------------------------------------------------------------------
// attn scale-chunk NCHW (bf16) -> NHWC-p bf16. grid (128, 16).
// ---------------------------------------------------------------------------
__global__ __launch_bounds__(256) void attn2nhwc_kernel(
    const ushort_t* __restrict__ in, ushort_t* __restrict__ out)
{
    __shared__ ushort_t tile[128 * 136];
    const int img = blockIdx.y, hh = blockIdx.x;
    const int tid = threadIdx.x;
    #pragma unroll
    for (int i = 0; i < 8; ++i) {
        int idx = tid + 256 * i;
        int c = idx >> 4, w8 = (idx & 15) * 8;
        size_t src = (((size_t)((c >> 5) * 16 + img)) * 32 + (c & 31)) * (size_t)HW_
                     + hh * 128 + w8;
        uint4 raw = *(const uint4*)&in[src];
        ushort_t v[8];
        v[0] = raw.x & 0xffffu; v[1] = raw.x >> 16;
        v[2] = raw.y & 0xffffu; v[3] = raw.y >> 16;
        v[4] = raw.z & 0xffffu; v[5] = raw.z >> 16;
        v[6] = raw.w & 0xffffu; v[7] = raw.w >> 16;
        #pragma unroll
        for (int k = 0; k < 8; ++k) {
            int w = w8 + k;
            int g = (c >> 3) ^ ((w >> 3) & 7);
            tile[w * 136 + g * 8 + (c & 7)] = v[k];
        }
    }
    __syncthreads();
    #pragma unroll
    for (int i = 0; i < 8; ++i) {
        int idx = tid + 256 * i;
        int w = idx >> 4, g = idx & 15;
        int gs = g ^ ((w >> 3) & 7);
        uint4 raw = *(const uint4*)&tile[w * 136 + gs * 8];
        int c8 = g * 8;
        size_t off = (((size_t)(img * 128 + hh)) * 8 + (c8 >> 4)) * 2048 + w * 16 + (c8 & 8);
        *(uint4*)&out[off] = raw;
    }
}

// ---------------------------------------------------------------------------
// qkv MFMA v5: fused q+k+v, 768 threads, depth-2 prefetch. Epilogue deposits
// to LDS tiles [c_local][136-pad px] then writes CONTIGUOUS 32*psz-elem
// blocks per token (permuted dd ordering) -> dense coalesced stores.
// grid (128, 16), block 768.
// ---------------------------------------------------------------------------
__global__ __launch_bounds__(768, 1) void qkvm_kernel(
    const ushort_t* __restrict__ xn, const ushort_t* __restrict__ Wqkv,
    const float* __restrict__ bq, const float* __restrict__ bk,
    const float* __restrict__ bv,
    ushort_t* __restrict__ qw, ushort_t* __restrict__ kw,
    ushort_t* __restrict__ vw)
{
    // staging: 3 bufs x 2048 (12 KB, aliased) | tiles: 6 x 32 x 136 = 26112 (51 KB)
    __shared__ ushort_t lds[26112];
    const int h = blockIdx.x, img = blockIdx.y;
    const int tid = threadIdx.x, lane = tid & 63, wv = tid >> 6;
    const int w3 = wv >> 2, iw = wv & 3;
    const int pxh = iw & 1, coh = iw >> 1;
    const int kch = lane >> 5;
    const ushort_t* Wb = Wqkv + (size_t)w3 * 16384;
    const float* bias = (w3 == 0) ? bq : ((w3 == 1) ? bk : bv);
    const int b_ = img >> 2, t_ = img & 3;

    f32x16 acc[2][2];
    #pragma unroll
    for (int i = 0; i < 2; ++i)
        #pragma unroll
        for (int j = 0; j < 2; ++j)
            #pragma unroll
            for (int k = 0; k < 16; ++k) acc[i][j][k] = 0.f;

    auto STAGE = [&](int p, int b) {
        if (w3 == 0) {
            int kb = iw;
            int px = kb * 32 + (lane >> 1), ch = lane & 1;
            int cg = ch ^ ((px >> 2) & 1);
            const ushort_t* src = xn + (((size_t)(img * 128 + h)) * 8 + p) * 2048
                                  + px * 16 + cg * 8;
            async16(src, (char*)lds + b * 4096 + kb * 1024);
        }
    };

    STAGE(0, 0);
    STAGE(1, 1);
    #pragma unroll
    for (int p = 0; p < 8; ++p) {
        const int fbase = p * 4 + coh * 2;
        bf16x8 wa0 = *(const bf16x8*)(Wb + ((size_t)fbase * 64 + lane) * 8);
        bf16x8 wa1 = *(const bf16x8*)(Wb + ((size_t)(fbase + 1) * 64 + lane) * 8);
        asm volatile("" ::: "memory");
        if (p < 6) STAGE(p + 2, (p + 2) % 3);
        if (p < 6)      asm volatile("s_waitcnt vmcnt(4)" ::: "memory");
        else if (p == 6) asm volatile("s_waitcnt vmcnt(3)" ::: "memory");
        else             asm volatile("s_waitcnt vmcnt(2)" ::: "memory");
        __builtin_amdgcn_s_barrier();
        __builtin_amdgcn_s_setprio(1);
        const ushort_t* bbuf = lds + (p % 3) * 2048;
        #pragma unroll
        for (int i = 0; i < 2; ++i) {
            int px = pxh * 64 + i * 32 + (lane & 31);
            int s = kch ^ ((px >> 2) & 1);
            bf16x8 bv4 = *(const bf16x8*)(bbuf + px * 16 + s * 8);
            acc[i][0] = __builtin_amdgcn_mfma_f32_32x32x16_bf16(wa0, bv4, acc[i][0], 0, 0, 0);
            acc[i][1] = __builtin_amdgcn_mfma_f32_32x32x16_bf16(wa1, bv4, acc[i][1], 0, 0, 0);
        }
        __builtin_amdgcn_s_setprio(0);
        __builtin_amdgcn_s_barrier();
    }

    // ---- epilogue: per j, deposit [c_local][px] tiles, then contiguous writes
    #pragma unroll
    for (int j = 0; j < 2; ++j) {
        __syncthreads();   // staging / previous-tile reads complete
        {
            const int scale = coh * 2 + j;
            ushort_t* tile = lds + (w3 * 2 + coh) * 4352;   // [c_local][136]
            #pragma unroll
            for (int rg = 0; rg < 16; ++rg) {
                int c_local = (rg & 3) + 8 * (rg >> 2) + 4 * kch;
                float bb = bias[scale * 32 + c_local];
                #pragma unroll
                for (int i = 0; i < 2; ++i) {
                    int px = pxh * 64 + i * 32 + (lane & 31);
                    tile[c_local * 136 + px] = (ushort_t)f2bf(acc[i][j][rg] + bb);
                }
            }
        }
        __syncthreads();
        // 3072 uint4 runs; consecutive threads -> consecutive global addresses
        #pragma unroll
        for (int l = 0; l < 4; ++l) {
            int idx = l * 768 + tid;                 // 0..3071
            int g3 = idx >> 10, rem = idx & 1023;
            int coh_t = rem >> 9, rem2 = rem & 511;
            int scale = coh_t * 2 + j;
            int lg = 6 - scale;
            int ow = rem2 >> (lg + 2);
            int rem3 = rem2 & ((1 << (lg + 2)) - 1);
            int c_local = rem3 >> (lg - 3);
            int pw0 = (rem3 & ((1 << (lg - 3)) - 1)) << 3;
            int outn = 128 >> lg;
            int Dd = 32 << (2 * lg);
            int oh = h >> lg, ph = h & ((1 << lg) - 1);
            ushort_t* outp = (g3 == 0) ? qw : ((g3 == 1) ? kw : vw);
            size_t off = (size_t)scale * 8388608u
                + ((size_t)((b_ * 4 + t_) * outn * outn + oh * outn + ow)) * (size_t)Dd
                + ((size_t)ph << (lg + 5)) + (c_local << lg) + pw0;
            uint4 raw = *(const uint4*)&lds[(g3 * 2 + coh_t) * 4352 + c_local * 136
                                            + (ow << lg) + pw0];
            *(uint4*)&outp[off] = raw;
        }
    }
}

// ---------------------------------------------------------------------------
// V transpose, all scales fused (unchanged; dd-permutation agnostic). grid 6144.
// ---------------------------------------------------------------------------
__device__ __forceinline__ void vtrans_dev(
    const ushort_t* __restrict__ src, ushort_t* __restrict__ dst,
    int n, int Dd, int xb, int yb, int b_)
{
    const int ddb = xb * 128, tokb = yb * 128;
    const int tid = threadIdx.x;
    const int ti = tid & 15, tj = tid >> 4;
    const int tok0 = tokb + ti * 8, dd0 = ddb + tj * 8;
    if (tok0 >= n) return;
    const ushort_t* s = src + (size_t)b_ * (size_t)n * Dd;
    ushort_t* d = dst + (size_t)b_ * (size_t)n * Dd;
    ushort_t a[8][8];
    #pragma unroll
    for (int e = 0; e < 8; ++e)
        *(uint4*)a[e] = *(const uint4*)&s[(size_t)(tok0 + e) * Dd + dd0];
    #pragma unroll
    for (int q = 0; q < 8; ++q) {
        ushort_t o[8];
        #pragma unroll
        for (int e = 0; e < 8; ++e) o[e] = a[e][q];
        *(uint4*)&d[(size_t)(dd0 + q) * n + tok0] = *(uint4*)o;
    }
}

__global__ __launch_bounds__(256) void vtrans_all_kernel(
    const ushort_t* __restrict__ vw, ushort_t* __restrict__ vt)
{
    const int bid = blockIdx.x;
    if (bid < 4096) {
        int sid = bid;
        vtrans_dev(vw + 0u, vt + 0u, 16, 131072, sid & 1023, 0, sid >> 10);
    } else if (bid < 5120) {
        int sid = bid - 4096;
        vtrans_dev(vw + 8388608u, vt + 8388608u, 64, 32768, sid & 255, 0, sid >> 8);
    } else if (bid < 5632) {
        int sid = bid - 5120;
        vtrans_dev(vw + 16777216u, vt + 16777216u, 256, 8192, sid & 63, (sid >> 6) & 1, sid >> 7);
    } else {
        int sid = bid - 5632;
        vtrans_dev(vw + 25165824u, vt + 25165824u, 1024, 2048, sid & 15, (sid >> 4) & 7, sid >> 7);
    }
}

// ---------------------------------------------------------------------------
// scores, LDS-tiled (s3, s2) — unchanged (whole-row dots, dd-agnostic).
// ---------------------------------------------------------------------------
template<int LG, int KS>
__device__ __forceinline__ void scores_lds_dev(
    const ushort_t* __restrict__ qw, const ushort_t* __restrict__ kw,
    float* __restrict__ sc_s, int bx, int by, int b_, int ks, ushort_t* lds)
{
    constexpr int outn = 128 >> LG;
    constexpr int n = 4 * outn * outn;
    constexpr int Dd = 32 << (2 * LG);
    constexpr int scale = 6 - LG;
    constexpr int DdK = Dd / KS;
    constexpr int NPH = DdK / 64;
    const size_t base = (size_t)scale * 8388608u;
    const int tid = threadIdx.x, lane = tid & 63, wv = tid >> 6;
    const ushort_t* qb = qw + base + (size_t)b_ * (size_t)n * Dd;
    const ushort_t* kb = kw + base + (size_t)b_ * (size_t)n * Dd;
    float* scb = sc_s + (size_t)b_ * n * n;
    const float scl = rsqrtf((float)Dd);
    const int mb = bx * 128, nb = by * 128;
    const int mbl = (wv & 1) * 64, nbl = (wv >> 1) * 64;
    const int k0beg = ks * DdK;

    f32x16 acc[2][2];
    #pragma unroll
    for (int i = 0; i < 2; ++i)
        #pragma unroll
        for (int j = 0; j < 2; ++j)
            #pragma unroll
            for (int k = 0; k < 16; ++k) acc[i][j][k] = 0.f;

    auto STAGE = [&](int k0, int buf) {
        #pragma unroll
        for (int l = 0; l < 4; ++l) {
            int id = l * 256 + tid;
            int row = id >> 3, ch = id & 7;
            int sw = ch ^ (row & 7);
            async16(qb + (size_t)(mb + row) * Dd + k0 + sw * 8,
                    (char*)lds + buf * 32768 + id * 16);
        }
        #pragma unroll
        for (int l = 0; l < 4; ++l) {
            int id = l * 256 + tid;
            int row = id >> 3, ch = id & 7;
            int sw = ch ^ (row & 7);
            async16(kb + (size_t)(nb + row) * Dd + k0 + sw * 8,
                    (char*)lds + buf * 32768 + 16384 + id * 16);
        }
    };

    STAGE(k0beg, 0);
    for (int p = 0; p < NPH; ++p) {
        if (p + 1 < NPH) STAGE(k0beg + (p + 1) * 64, (p + 1) & 1);
        if (p + 1 < NPH) asm volatile("s_waitcnt vmcnt(8)" ::: "memory");
        else             asm volatile("s_waitcnt vmcnt(0)" ::: "memory");
        __builtin_amdgcn_s_barrier();
        __builtin_amdgcn_s_setprio(1);
        const ushort_t* bufA = lds + (p & 1) * 16384;
        const ushort_t* bufB = bufA + 8192;
        #pragma unroll
        for (int u = 0; u < 4; ++u) {
            const int c = u * 2 + (lane >> 5);
            bf16x8 a[2], b[2];
            #pragma unroll
            for (int i = 0; i < 2; ++i) {
                int row = mbl + i * 32 + (lane & 31);
                a[i] = *(const bf16x8*)(bufA + row * 64 + ((c ^ (row & 7)) << 3));
            }
            #pragma unroll
            for (int j = 0; j < 2; ++j) {
                int row = nbl + j * 32 + (lane & 31);
                b[j] = *(const bf16x8*)(bufB + row * 64 + ((c ^ (row & 7)) << 3));
            }
            #pragma unroll
            for (int i = 0; i < 2; ++i)
                #pragma unroll
                for (int j = 0; j < 2; ++j)
                    acc[i][j] = __builtin_amdgcn_mfma_f32_32x32x16_bf16(a[i], b[j], acc[i][j], 0, 0, 0);
        }
        __builtin_amdgcn_s_setprio(0);
        __builtin_amdgcn_s_barrier();
    }

    #pragma unroll
    for (int i = 0; i < 2; ++i)
        #pragma unroll
        for (int j = 0; j < 2; ++j)
            #pragma unroll
            for (int rg = 0; rg < 16; ++rg) {
                int row = mb + mbl + i * 32 + (rg & 3) + 8 * (rg >> 2) + 4 * (lane >> 5);
                int col = nb + nbl + j * 32 + (lane & 31);
                float v = acc[i][j][rg] * scl;
                size_t off = (size_t)row * n + col;
                if (KS == 1) scb[off] = v;
                else atomicAdd(&scb[off], v);
            }
}

// ---------------------------------------------------------------------------
// scores direct body (s1 CFG1, s0 CFG2) — unchanged.
// ---------------------------------------------------------------------------
template<int CFG, int LG, int KS>
__device__ __forceinline__ void scores_dev(
    const ushort_t* __restrict__ qw, const ushort_t* __restrict__ kw,
    float* __restrict__ sc_s, int b_, int ks)
{
    constexpr int outn = 128 >> LG;
    constexpr int n = 4 * outn * outn;
    constexpr int Dd = 32 << (2 * LG);
    constexpr int scale = 6 - LG;
    constexpr int DdK = Dd / KS;
    const size_t base = (size_t)scale * 8388608u;
    const int tid = threadIdx.x, lane = tid & 63, wv = tid >> 6;
    const ushort_t* qb = qw + base + (size_t)b_ * (size_t)n * Dd;
    const ushort_t* kb = kw + base + (size_t)b_ * (size_t)n * Dd;
    float* scb = sc_s + (size_t)b_ * n * n;
    const float scl = rsqrtf((float)Dd);
    const int koff = (lane >> 5) * 8;
    const int mbq = (CFG == 1) ? (wv & 1) * 32 : 0;
    const int nbq = (CFG == 1) ? (wv >> 1) * 32 : 0;

    f32x16 acc;
    #pragma unroll
    for (int k = 0; k < 16; ++k) acc[k] = 0.f;

    int mrow = mbq + (lane & 31);
    int nrow = nbq + (lane & 31);
    if (CFG == 2) { if (mrow >= n) mrow = n - 1; if (nrow >= n) nrow = n - 1; }
    int k0beg = ks * DdK, k0end = k0beg + DdK;
    if (CFG == 2) { constexpr int DdW = DdK >> 2; k0beg += wv * DdW; k0end = k0beg + DdW; }

    for (int k0 = k0beg; k0 < k0end; k0 += 64) {
        bf16x8 a[4], b[4];
        #pragma unroll
        for (int u = 0; u < 4; ++u) {
            a[u] = *(const bf16x8*)(qb + (size_t)mrow * Dd + k0 + u * 16 + koff);
            b[u] = *(const bf16x8*)(kb + (size_t)nrow * Dd + k0 + u * 16 + koff);
        }
        #pragma unroll
        for (int u = 0; u < 4; ++u)
            acc = __builtin_amdgcn_mfma_f32_32x32x16_bf16(a[u], b[u], acc, 0, 0, 0);
    }

    #pragma unroll
    for (int rg = 0; rg < 16; ++rg) {
        int row = mbq + (rg & 3) + 8 * (rg >> 2) + 4 * (lane >> 5);
        int col = nbq + (lane & 31);
        if (CFG == 2 && (row >= n || col >= n)) continue;
        float v = acc[rg] * scl;
        size_t off = (size_t)row * n + col;
        atomicAdd(&scb[off], v);
    }
}

// fused: 1024 blocks, heavy s3 first, per-segment XCD swizzle
__global__ __launch_bounds__(256, 2) void scores_all_kernel(
    const ushort_t* __restrict__ qw, const ushort_t* __restrict__ kw,
    float* __restrict__ sc)
{
    __shared__ ushort_t slds[32768];   // 64 KB: 2 bufs x (A 16KB + B 16KB)
    const int bid = blockIdx.x;
    if (bid < 256) {                 // s3: 8x8x4, KS=1
        int l = bid;            int sid = (l & 7) * 32 + (l >> 3);
        scores_lds_dev<3, 1>(qw, kw, sc + SC_OFF3, sid & 7, (sid >> 3) & 7, sid >> 6, 0, slds);
    } else if (bid < 512) {          // s2: 2x2x4x16ks
        int l = bid - 256;      int sid = (l & 7) * 32 + (l >> 3);
        scores_lds_dev<4, 16>(qw, kw, sc + SC_OFF2, sid & 1, (sid >> 1) & 1, sid >> 6, (sid >> 2) & 15, slds);
    } else if (bid < 768) {          // s1: 4x64ks
        int l = bid - 512;      int sid = (l & 7) * 32 + (l >> 3);
        scores_dev<1, 5, 64>(qw, kw, sc + SC_OFF1, sid >> 6, sid & 63);
    } else {                         // s0: 4x64ks
        int l = bid - 768;      int sid = (l & 7) * 32 + (l >> 3);
        scores_dev<2, 6, 64>(qw, kw, sc + SC_OFF0, sid >> 6, sid & 63);
    }
}

// ---------------------------------------------------------------------------
// softmax fused over all scales (unchanged). grid 5440.
// ---------------------------------------------------------------------------
__global__ __launch_bounds__(256) void softmax_all_kernel(
    const float* __restrict__ sc, ushort_t* __restrict__ pbf)
{
    const int bid = blockIdx.x;
    int n; size_t off; int row;
    if (bid < 64)        { n = 16;   row = bid;        off = SC_OFF0; }
    else if (bid < 320)  { n = 64;   row = bid - 64;   off = SC_OFF1; }
    else if (bid < 1344) { n = 256;  row = bid - 320;  off = SC_OFF2; }
    else                 { n = 1024; row = bid - 1344; off = SC_OFF3; }
    const float* p = sc + off + (size_t)row * n;
    ushort_t* q = pbf + off + (size_t)row * n;
    const int tid = threadIdx.x;
    float v[4];
    #pragma unroll
    for (int j = 0; j < 4; ++j) { int idx = tid + 256 * j; v[j] = (idx < n) ? p[idx] : -3.0e38f; }
    float m = fmaxf(fmaxf(v[0], v[1]), fmaxf(v[2], v[3]));
    #pragma unroll
    for (int off2 = 32; off2 >= 1; off2 >>= 1) m = fmaxf(m, __shfl_xor(m, off2));
    __shared__ float red[4];
    const int wid = tid >> 6, lane = tid & 63;
    if (lane == 0) red[wid] = m;
    __syncthreads();
    m = fmaxf(fmaxf(red[0], red[1]), fmaxf(red[2], red[3]));
    float e[4]; float s = 0.f;
    #pragma unroll
    for (int j = 0; j < 4; ++j) { int idx = tid + 256 * j; e[j] = (idx < n) ? __expf(v[j] - m) : 0.f; s += e[j]; }
    #pragma unroll
    for (int off2 = 32; off2 >= 1; off2 >>= 1) s += __shfl_xor(s, off2);
    __syncthreads();
    if (lane == 0) red[wid] = s;
    __syncthreads();
    s = red[0] + red[1] + red[2] + red[3];
    float inv = 1.0f / s;
    #pragma unroll
    for (int j = 0; j < 4; ++j) {
        int idx = tid + 256 * j;
        if (idx < n) q[idx] = (ushort_t)f2bf(e[j] * inv);
    }
}

// ---------------------------------------------------------------------------
// PV, LDS-tiled (s3, s2): permuted-dd decode in epilogue.
// ---------------------------------------------------------------------------
template<int LG>
__device__ __forceinline__ void pvm_lds_dev(
    const ushort_t* __restrict__ pbf_s, const ushort_t* __restrict__ vt,
    ushort_t* __restrict__ attn, int bx, int by, int b_, ushort_t* lds)
{
    constexpr int outn = 128 >> LG, psz = 1 << LG;
    constexpr int n = 4 * outn * outn;
    constexpr int Dd = 32 << (2 * LG);
    constexpr int scale = 6 - LG;
    constexpr int NPH = n / 64;
    const int tid = threadIdx.x, lane = tid & 63, wv = tid >> 6;
    const ushort_t* pb = pbf_s + (size_t)b_ * n * n;
    const ushort_t* vb = vt + (size_t)scale * 8388608u + (size_t)b_ * (size_t)Dd * n;
    const int mb = by * 128;        // tok base
    const int nb = bx * 128;        // dd base
    const int mbl = (wv & 1) * 64, nbl = (wv >> 1) * 64;

    f32x16 acc[2][2];
    #pragma unroll
    for (int i = 0; i < 2; ++i)
        #pragma unroll
        for (int j = 0; j < 2; ++j)
            #pragma unroll
            for (int k = 0; k < 16; ++k) acc[i][j][k] = 0.f;

    auto STAGE = [&](int k0, int buf) {
        #pragma unroll
        for (int l = 0; l < 4; ++l) {
            int id = l * 256 + tid;
            int row = id >> 3, ch = id & 7;
            int sw = ch ^ (row & 7);
            async16(pb + (size_t)(mb + row) * n + k0 + sw * 8,
                    (char*)lds + buf * 32768 + id * 16);
        }
        #pragma unroll
        for (int l = 0; l < 4; ++l) {
            int id = l * 256 + tid;
            int row = id >> 3, ch = id & 7;
            int sw = ch ^ (row & 7);
            async16(vb + (size_t)(nb + row) * n + k0 + sw * 8,
                    (char*)lds + buf * 32768 + 16384 + id * 16);
        }
    };

    STAGE(0, 0);
    for (int p = 0; p < NPH; ++p) {
        if (p + 1 < NPH) STAGE((p + 1) * 64, (p + 1) & 1);
        if (p + 1 < NPH) asm volatile("s_waitcnt vmcnt(8)" ::: "memory");
        else             asm volatile("s_waitcnt vmcnt(0)" ::: "memory");
        __builtin_amdgcn_s_barrier();
        __builtin_amdgcn_s_setprio(1);
        const ushort_t* bufA = lds + (p & 1) * 16384;
        const ushort_t* bufB = bufA + 8192;
        #pragma unroll
        for (int u = 0; u < 4; ++u) {
            const int c = u * 2 + (lane >> 5);
            bf16x8 a[2], b[2];
            #pragma unroll
            for (int i = 0; i < 2; ++i) {
                int row = mbl + i * 32 + (lane & 31);
                a[i] = *(const bf16x8*)(bufA + row * 64 + ((c ^ (row & 7)) << 3));
            }
            #pragma unroll
            for (int j = 0; j < 2; ++j) {
                int row = nbl + j * 32 + (lane & 31);
                b[j] = *(const bf16x8*)(bufB + row * 64 + ((c ^ (row & 7)) << 3));
            }
            #pragma unroll
            for (int i = 0; i < 2; ++i)
                #pragma unroll
                for (int j = 0; j < 2; ++j)
                    acc[i][j] = __builtin_amdgcn_mfma_f32_32x32x16_bf16(a[i], b[j], acc[i][j], 0, 0, 0);
        }
        __builtin_amdgcn_s_setprio(0);
        __builtin_amdgcn_s_barrier();
    }

    constexpr int lgo = 7 - LG;
    #pragma unroll
    for (int i = 0; i < 2; ++i)
        #pragma unroll
        for (int j = 0; j < 2; ++j)
            #pragma unroll
            for (int rg = 0; rg < 16; ++rg) {
                int tok = mb + mbl + i * 32 + (rg & 3) + 8 * (rg >> 2) + 4 * (lane >> 5);
                int dd = nb + nbl + j * 32 + (lane & 31);
                // permuted dd: ph, c_local, pw
                int ph = dd >> (LG + 5);
                int r2 = dd & ((1 << (LG + 5)) - 1);
                int c_local = r2 >> LG;
                int pw = r2 & (psz - 1);
                int t_ = tok >> (2 * lgo);
                int rem = tok & ((1 << (2 * lgo)) - 1);
                int oh = rem >> lgo, ow = rem & (outn - 1);
                size_t off = (((size_t)(scale * 16 + b_ * 4 + t_) * 32 + c_local) * 128
                              + ((oh << LG) + ph)) * 128 + ((ow << LG) + pw);
                attn[off] = (ushort_t)f2bf(acc[i][j][rg]);
            }
}

// ---------------------------------------------------------------------------
// PV direct body (s1 CFG1, s0 CFG2): permuted-dd decode.
// ---------------------------------------------------------------------------
template<int CFG, int LG>
__device__ __forceinline__ void pvm_dev(
    const ushort_t* __restrict__ pbf_s, const ushort_t* __restrict__ vt,
    ushort_t* __restrict__ attn, int bx, int by, int b_)
{
    constexpr int outn = 128 >> LG, psz = 1 << LG;
    constexpr int n = 4 * outn * outn;
    constexpr int Dd = 32 << (2 * LG);
    constexpr int scale = 6 - LG;
    const int tid = threadIdx.x, lane = tid & 63, wv = tid >> 6;
    const ushort_t* pb = pbf_s + (size_t)b_ * n * n;
    const ushort_t* vb = vt + (size_t)scale * 8388608u + (size_t)b_ * (size_t)Dd * n;
    const int mb = (CFG == 1) ? (wv & 1) * 32 : 0;
    const int nb = (CFG == 1) ? bx * 128 + (wv >> 1) * 64
                              : bx * 256 + wv * 64;
    const int koff = (lane >> 5) * 8;

    f32x16 acc[2];
    #pragma unroll
    for (int j = 0; j < 2; ++j)
        #pragma unroll
        for (int k = 0; k < 16; ++k) acc[j][k] = 0.f;

    int mr = mb + (lane & 31);
    if (CFG == 2 && mr >= n) mr = n - 1;
    const int nr0 = nb + (lane & 31), nr1 = nr0 + 32;

    if constexpr (CFG == 2) {
        bf16x8 b0 = *(const bf16x8*)(vb + (size_t)nr0 * n + koff);
        bf16x8 b1 = *(const bf16x8*)(vb + (size_t)nr1 * n + koff);
        bf16x8 a = *(const bf16x8*)(pb + (size_t)mr * n + koff);
        acc[0] = __builtin_amdgcn_mfma_f32_32x32x16_bf16(a, b0, acc[0], 0, 0, 0);
        acc[1] = __builtin_amdgcn_mfma_f32_32x32x16_bf16(a, b1, acc[1], 0, 0, 0);
    } else {
        for (int k0 = 0; k0 < n; k0 += 64) {
            bf16x8 vb0[4], vb1[4], pa[4];
            #pragma unroll
            for (int u = 0; u < 4; ++u) {
                vb0[u] = *(const bf16x8*)(vb + (size_t)nr0 * n + k0 + u * 16 + koff);
                vb1[u] = *(const bf16x8*)(vb + (size_t)nr1 * n + k0 + u * 16 + koff);
                pa[u]  = *(const bf16x8*)(pb + (size_t)mr * n + k0 + u * 16 + koff);
            }
            #pragma unroll
            for (int u = 0; u < 4; ++u) {
                acc[0] = __builtin_amdgcn_mfma_f32_32x32x16_bf16(pa[u], vb0[u], acc[0], 0, 0, 0);
                acc[1] = __builtin_amdgcn_mfma_f32_32x32x16_bf16(pa[u], vb1[u], acc[1], 0, 0, 0);
            }
        }
    }

    constexpr int lgo = 7 - LG;
    #pragma unroll
    for (int j = 0; j < 2; ++j)
        #pragma unroll
        for (int rg = 0; rg < 16; ++rg) {
            int tok = mb + (rg & 3) + 8 * (rg >> 2) + 4 * (lane >> 5);
            if (CFG == 2 && tok >= n) continue;
            int dd = nb + j * 32 + (lane & 31);
            // permuted dd: ph, c_local, pw
            int ph = dd >> (LG + 5);
            int r2 = dd & ((1 << (LG + 5)) - 1);
            int c_local = r2 >> LG;
            int pw = r2 & (psz - 1);
            int t_ = tok >> (2 * lgo);
            int rem = tok & ((1 << (2 * lgo)) - 1);
            int oh = rem >> lgo, ow = rem & (outn - 1);
            size_t off = (((size_t)(scale * 16 + b_ * 4 + t_) * 32 + c_local) * 128
                          + ((oh << LG) + ph)) * 128 + ((ow << LG) + pw);
            attn[off] = (ushort_t)f2bf(acc[j][rg]);
        }
}

// fused: 4096 blocks, heavy s3 first, per-segment XCD swizzle
__global__ __launch_bounds__(256, 2) void pvm_all_kernel(
    const ushort_t* __restrict__ pbf, const ushort_t* __restrict__ vt,
    ushort_t* __restrict__ attn)
{
    __shared__ ushort_t plds[32768];   // 64 KB: 2 bufs x (P 16KB + V 16KB)
    const int bid = blockIdx.x;
    if (bid < 512) {                 // s3: 16x8x4 (LDS-tiled)
        int l = bid;            int sid = (l & 7) * 64 + (l >> 3);
        pvm_lds_dev<3>(pbf + SC_OFF3, vt, attn, sid & 15, (sid >> 4) & 7, sid >> 7, plds);
    } else if (bid < 1024) {         // s2: 64x2x4 (LDS-tiled)
        int l = bid - 512;      int sid = (l & 7) * 64 + (l >> 3);
        pvm_lds_dev<4>(pbf + SC_OFF2, vt, attn, sid & 63, (sid >> 6) & 1, sid >> 7, plds);
    } else if (bid < 2048) {         // s1: 256x4
        int l = bid - 1024;     int sid = (l & 7) * 128 + (l >> 3);
        pvm_dev<1, 5>(pbf + SC_OFF1, vt, attn, sid & 255, 0, sid >> 8);
    } else {                         // s0: 512x4
        int l = bid - 2048;     int sid = (l & 7) * 256 + (l >> 3);
        pvm_dev<2, 6>(pbf + SC_OFF0, vt, attn, sid & 511, 0, sid >> 9);
    }
}

// ---------------------------------------------------------------------------
// MFMA implicit-GEMM 3x3 conv v5 (unchanged from r12).
// ---------------------------------------------------------------------------
template<int DIL, int MODE>
__global__ __launch_bounds__(256, 2) void conv3x_kernel(
    const ushort_t* __restrict__ in, const ushort_t* __restrict__ Wp,
    const float* __restrict__ bias, const ushort_t* __restrict__ resn,
    float* __restrict__ outf, ushort_t* __restrict__ outn,
    const ushort_t* __restrict__ zp)
{
    __shared__ ushort_t lds[34816];
    const int fid = blockIdx.y * 64 + blockIdx.x;        // 0..1023
    const int nfid = (fid & 7) * 128 + (fid >> 3);       // XCD-bijective
    const int img = nfid >> 6, rp = nfid & 63;
    const int h0 = (DIL == 1) ? rp * 2 : ((rp & 1) + (rp >> 1) * 4);
    const int tid = threadIdx.x, lane = tid & 63, wv = tid >> 6;
    const int pxh = wv & 1, coq = wv >> 1;
    const int kch = lane >> 5;

    f32x16 acc[2][2][2];   // [row][i(px)][tn]
    #pragma unroll
    for (int r = 0; r < 2; ++r)
        #pragma unroll
        for (int i = 0; i < 2; ++i)
            #pragma unroll
            for (int j = 0; j < 2; ++j)
                #pragma unroll
                for (int k = 0; k < 16; ++k) acc[r][i][j][k] = 0.f;

    auto STAGE = [&](int p, int b) {
        #pragma unroll
        for (int kb = wv; kb < 20; kb += 4) {      // 5 loads per wave
            int slot = kb / 5, pg = kb % 5;
            int pxi = pg * 32 + (lane >> 1);
            int wc = pxi - 16;
            int ir = h0 - DIL + slot * DIL;
            int cg = (lane & 1) ^ ((pxi >> 2) & 1);
            const ushort_t* src;
            if (wc >= 0 && wc < 128 && ir >= 0 && ir < 128)
                src = in + (((size_t)(img * 128 + ir)) * 8 + p) * 2048 + wc * 16 + cg * 8;
            else
                src = zp + lane * 8;
            async16(src, (char*)lds + b * 20480 + kb * 1024);
        }
    };

    STAGE(0, 0);
    #pragma unroll
    for (int p = 0; p < 8; ++p) {
        bf16x8 w0[9], w1[9];
        #pragma unroll
        for (int tap = 0; tap < 9; ++tap) {
            int fbase = (((p >> 1) * 9 + tap) * 2 + (p & 1)) * 4 + coq * 2;
            w0[tap] = *(const bf16x8*)(Wp + ((size_t)fbase * 64 + lane) * 8);
            w1[tap] = *(const bf16x8*)(Wp + ((size_t)(fbase + 1) * 64 + lane) * 8);
        }
        asm volatile("" ::: "memory");
        if (p < 7) STAGE(p + 1, (p + 1) & 1);
        if (p < 7) asm volatile("s_waitcnt vmcnt(23)" ::: "memory");
        else       asm volatile("s_waitcnt vmcnt(18)" ::: "memory");
        __builtin_amdgcn_s_barrier();
        __builtin_amdgcn_s_setprio(1);
        const ushort_t* bbuf = lds + (p & 1) * 10240;
        #pragma unroll
        for (int tap = 0; tap < 9; ++tap) {
            const int tr = tap / 3, tc = tap % 3;
            #pragma unroll
            for (int r = 0; r < 2; ++r) {
                const ushort_t* sb = bbuf + (r + tr) * 2560;
                #pragma unroll
                for (int i = 0; i < 2; ++i) {
                    int pxi = pxh * 64 + i * 32 + (lane & 31) + (tc - 1) * DIL + 16;
                    int s = kch ^ ((pxi >> 2) & 1);
                    bf16x8 bv = *(const bf16x8*)(sb + pxi * 16 + s * 8);
                    acc[r][i][0] = __builtin_amdgcn_mfma_f32_32x32x16_bf16(w0[tap], bv, acc[r][i][0], 0, 0, 0);
                    acc[r][i][1] = __builtin_amdgcn_mfma_f32_32x32x16_bf16(w1[tap], bv, acc[r][i][1], 0, 0, 0);
                }
            }
        }
        __builtin_amdgcn_s_setprio(0);
        __builtin_amdgcn_s_barrier();
    }
    __syncthreads();

    if (MODE == 0 || MODE == 2) {
        #pragma unroll
        for (int r = 0; r < 2; ++r) {
            const int hr = h0 + r * DIL;
            for (int u = tid; u < 2048; u += 256) {
                int px = u >> 4, c8 = (u & 15) * 8;
                size_t soff = (((size_t)(img * 128 + hr)) * 8 + (c8 >> 4)) * 2048 + px * 16 + (c8 & 8);
                *(uint4*)&lds[r * 17408 + px * 136 + c8] = *(const uint4*)&resn[soff];
            }
        }
        __syncthreads();
    }
    #pragma unroll
    for (int r = 0; r < 2; ++r) {
        const int hr = h0 + r * DIL;
        #pragma unroll
        for (int i = 0; i < 2; ++i)
            #pragma unroll
            for (int tn = 0; tn < 2; ++tn)
                #pragma unroll
                for (int rgq = 0; rgq < 4; ++rgq) {
                    const int cob = coq * 64 + tn * 32 + 8 * rgq + 4 * kch;
                    const int px = pxh * 64 + i * 32 + (lane & 31);
                    float v[4];
                    #pragma unroll
                    for (int e = 0; e < 4; ++e) {
                        float t = acc[r][i][tn][rgq * 4 + e] + bias[cob + e];
                        v[e] = (t >= 0.f) ? t : 0.2f * t;
                    }
                    if (MODE == 0) {
                        uint2 rr = *(const uint2*)&lds[r * 17408 + px * 136 + cob];
                        float w0v = bf2f(rr.x & 0xffffu) + v[0];
                        float w1v = bf2f(rr.x >> 16)     + v[1];
                        float w2v = bf2f(rr.y & 0xffffu) + v[2];
                        float w3v = bf2f(rr.y >> 16)     + v[3];
                        uint2 pk;
                        pk.x = f2bf(w0v) | (f2bf(w1v) << 16);
                        pk.y = f2bf(w2v) | (f2bf(w3v) << 16);
                        *(uint2*)&lds[r * 17408 + px * 136 + cob] = pk;
                    } else if (MODE == 1) {
                        uint2 pk;
                        pk.x = f2bf(v[0]) | (f2bf(v[1]) << 16);
                        pk.y = f2bf(v[2]) | (f2bf(v[3]) << 16);
                        *(uint2*)&lds[r * 17408 + px * 136 + cob] = pk;
                    } else {
                        uint2 rr = *(const uint2*)&lds[r * 17408 + px * 136 + cob];
                        float rv[4] = { bf2f(rr.x & 0xffffu), bf2f(rr.x >> 16),
                                        bf2f(rr.y & 0xffffu), bf2f(rr.y >> 16) };
                        #pragma unroll
                        for (int e = 0; e < 4; ++e)
                            outf[(((size_t)(img * 128 + cob + e)) * 128 + hr) * 128 + px] = rv[e] + v[e];
                    }
                }
    }
    if (MODE == 0 || MODE == 1) {
        __syncthreads();
        #pragma unroll
        for (int r = 0; r < 2; ++r) {
            const int hr = h0 + r * DIL;
            for (int u = tid; u < 2048; u += 256) {
                int px = u >> 4, c8 = (u & 15) * 8;
                size_t doff = (((size_t)(img * 128 + hr)) * 8 + (c8 >> 4)) * 2048 + px * 16 + (c8 & 8);
                *(uint4*)&outn[doff] = *(const uint4*)&lds[r * 17408 + px * 136 + c8];
            }
        }
    }
}

// ---------------------------------------------------------------------------
extern "C" void kernel_launch(void* const* d_in, const int* in_sizes, int n_in,
                              void* d_out, int out_size, void* d_ws, size_t ws_size,
                              hipStream_t stream)
{
    const float* x   = (const float*)d_in[0];
    const float* Wq  = (const float*)d_in[1];
    const float* bq  = (const float*)d_in[2];
    const float* Wk  = (const float*)d_in[3];
    const float* bk  = (const float*)d_in[4];
    const float* Wv  = (const float*)d_in[5];
    const float* bv  = (const float*)d_in[6];
    const float* Wo  = (const float*)d_in[7];
    const float* bo  = (const float*)d_in[8];
    const float* Wf1 = (const float*)d_in[9];
    const float* bf1 = (const float*)d_in[10];
    const float* Wf2 = (const float*)d_in[11];
    const float* bf2 = (const float*)d_in[12];
    float* out = (float*)d_out;
    char* ws = (char*)d_ws;
    const size_t MB = 1048576ull;
    ushort_t* qw   = (ushort_t*)(ws);                 // 64 MB; attnc alias; later ff1n
    ushort_t* kw   = (ushort_t*)(ws + 64 * MB);       // 64 MB; later vt; later x1n
    ushort_t* vw   = (ushort_t*)(ws + 128 * MB);      // 64 MB; later attn NHWC-p
    ushort_t* xn   = (ushort_t*)(ws + 192 * MB);      // 64 MB; x NHWC-p (lives to conv1)
    float*    sc   = (float*)   (ws + 256 * MB);      // 17.9 MB
    ushort_t* Wp   = (ushort_t*)(ws + 274 * MB);      // 864 KB
    ushort_t* Wqkv = (ushort_t*)(ws + 275 * MB);      // 96 KB
    ushort_t* zp   = (ushort_t*)(ws + 275 * MB + 256 * 1024);  // 1 KB zeros
    ushort_t* pbf  = (ushort_t*)(ws + 276 * MB);      // 8.95 MB
    ushort_t* attnc = qw;    // attn scale-chunk NCHW (qw dead after scores)
    ushort_t* vt    = kw;    // V^T all scales (kw dead after scores)
    ushort_t* nhwc  = vw;    // attn NHWC-p (vw dead after vtrans)
    ushort_t* x1n   = kw;    // x1 NHWC-p (vt dead after pvm)
    ushort_t* ff1n  = qw;    // ff1 NHWC-p (attnc dead after attn2nhwc)

    hipMemsetAsync(zp, 0, 1024, stream);
    hipMemsetAsync(sc + SC_OFF2, 0, (size_t)(SC_TOT - SC_OFF2) * 4, stream);
    prepack_kernel<<<dim3(576, 3), 256, 0, stream>>>(Wo, Wf1, Wf2, Wp);
    prepack1_kernel<<<dim3(64, 3), 256, 0, stream>>>(Wq, Wk, Wv, Wqkv);

    // 1) x -> NHWC-p, then fused q/k/v (input staged once)
    nchw2nhwc_kernel<<<dim3(128, 16), 256, 0, stream>>>(x, xn);
    qkvm_kernel<<<dim3(128, 16), 768, 0, stream>>>(xn, Wqkv, bq, bk, bv, qw, kw, vw);

    // 2) attention
    scores_all_kernel<<<dim3(1024), 256, 0, stream>>>(qw, kw, sc);
    vtrans_all_kernel<<<dim3(6144), 256, 0, stream>>>(vw, vt);   // kw dead -> vt
    softmax_all_kernel<<<dim3(5440), 256, 0, stream>>>(sc, pbf);
    pvm_all_kernel<<<dim3(4096), 256, 0, stream>>>(pbf, vt, attnc);

    // 3) attn chunks -> NHWC-p (into vw region)
    attn2nhwc_kernel<<<dim3(128, 16), 256, 0, stream>>>(attnc, nhwc);
    // 4) x1 = x + lrelu(conv3x3(attn)) -> x1n NHWC-p (kw region)
    conv3x_kernel<1, 0><<<dim3(64, 16), 256, 0, stream>>>(nhwc, Wp, bo, xn, nullptr, x1n, zp);
    // 5) ff1 = lrelu(conv3x3 dil2(x1)) -> ff1n NHWC-p (qw region)
    conv3x_kernel<2, 1><<<dim3(64, 16), 256, 0, stream>>>(x1n, Wp + 147456, bf1, nullptr, nullptr, ff1n, zp);
    // 6) out = x1 + lrelu(conv3x3(ff1)) -> d_out fp32 NCHW
    conv3x_kernel<1, 2><<<dim3(64, 16), 256, 0, stream>>>(ff1n, Wp + 2 * 147456, bf2, x1n, out, nullptr, zp);
}

// Round 17
// 565.727 us; speedup vs baseline: 1.1786x; 1.1140x over previous
//
#include <hip/hip_runtime.h>
#include <stdint.h>

#define C_   128
#define H_   128
#define W_   128
#define HW_  (128*128)

// sc/pbf per-scale element offsets (s3 first, then s2, s1, s0)
#define SC_OFF3 0
#define SC_OFF2 4194304
#define SC_OFF1 4456448
#define SC_OFF0 4472832
#define SC_TOT  4473856

typedef unsigned short ushort_t;
typedef __attribute__((ext_vector_type(8)))  short bf16x8;
typedef __attribute__((ext_vector_type(16))) float f32x16;

__device__ __forceinline__ float bf2f(uint32_t u) {
    union { float f; uint32_t i; } v; v.i = u << 16; return v.f;
}
__device__ __forceinline__ uint32_t f2bf(float f) {
    union { float f; uint32_t i; } v; v.f = f;
    uint32_t u = v.i;
    uint32_t r = u + 0x7FFFu + ((u >> 16) & 1u);
    return r >> 16;  // RTNE bf16 bits in low 16
}
__device__ __forceinline__ void async16(const ushort_t* g, void* l) {
    __builtin_amdgcn_global_load_lds(
        (const __attribute__((address_space(1))) unsigned int*)g,
        (__attribute__((address_space(3))) unsigned int*)l, 16, 0, 0);
}

// NHWC-p layout: element (img, h, c, w) at ((img*128+h)*8 + (c>>4))*2048 + w*16 + (c&15)
// attn scale-chunk NCHW: ((scale*16+img)*32 + c_local)*16384 + h*128 + w (aliases qw)
// windowed layout per scale (PERMUTED dd): base = scale*8388608 +
//   (b*Ntok + tok)*Dd + dd', where dd' = ph*(32*psz) + c_local*psz + pw.
// V^T (vt, aliases kw): vt + scale*8388608 + (b*Dd + dd')*n + tok

// ---------------------------------------------------------------------------
// prepack: conv weights (bx<576) + 1x1 qkv weights (bx>=576). grid (640, 3).
// ---------------------------------------------------------------------------
__global__ __launch_bounds__(256) void prepack_all_kernel(
    const float* __restrict__ Wo, const float* __restrict__ Wf1,
    const float* __restrict__ Wf2,
    const float* __restrict__ Wq, const float* __restrict__ Wk,
    const float* __restrict__ Wv,
    ushort_t* __restrict__ Wp, ushort_t* __restrict__ Wqkv)
{
    if (blockIdx.x < 576) {
        int t = blockIdx.x * 256 + threadIdx.x;          // 0..147455
        const float* W = (blockIdx.y == 0) ? Wo : ((blockIdx.y == 1) ? Wf1 : Wf2);
        ushort_t* dst = Wp + (size_t)blockIdx.y * 147456;
        int j = t & 7, lane = (t >> 3) & 63, f = t >> 9;
        int cot = f & 3, s = (f >> 2) & 1, tap = (f >> 3) % 9, cc = f / 72;
        int co = cot * 32 + (lane & 31);
        int ci = cc * 32 + s * 16 + (lane >> 5) * 8 + j;
        dst[t] = (ushort_t)f2bf(W[((size_t)co * 128 + ci) * 9 + tap]);
    } else {
        int t = (blockIdx.x - 576) * 256 + threadIdx.x;  // 0..16383
        const float* W = (blockIdx.y == 0) ? Wq : ((blockIdx.y == 1) ? Wk : Wv);
        ushort_t* dst = Wqkv + (size_t)blockIdx.y * 16384;
        int j = t & 7, lane = (t >> 3) & 63, f = t >> 9;  // f 0..31
        int cot = f & 3, s = f >> 2;
        int co = cot * 32 + (lane & 31);
        int ci = s * 16 + (lane >> 5) * 8 + j;
        dst[t] = (ushort_t)f2bf(W[(size_t)co * 128 + ci]);
    }
}

// ---------------------------------------------------------------------------
// attn scale-chunk NCHW (bf16) -> NHWC-p bf16. grid (128, 16).
// ---------------------------------------------------------------------------
__global__ __launch_bounds__(256) void attn2nhwc_kernel(
    const ushort_t* __restrict__ in, ushort_t* __restrict__ out)
{
    __shared__ ushort_t tile[128 * 136];
    const int img = blockIdx.y, hh = blockIdx.x;
    const int tid = threadIdx.x;
    #pragma unroll
    for (int i = 0; i < 8; ++i) {
        int idx = tid + 256 * i;
        int c = idx >> 4, w8 = (idx & 15) * 8;
        size_t src = (((size_t)((c >> 5) * 16 + img)) * 32 + (c & 31)) * (size_t)HW_
                     + hh * 128 + w8;
        uint4 raw = *(const uint4*)&in[src];
        ushort_t v[8];
        v[0] = raw.x & 0xffffu; v[1] = raw.x >> 16;
        v[2] = raw.y & 0xffffu; v[3] = raw.y >> 16;
        v[4] = raw.z & 0xffffu; v[5] = raw.z >> 16;
        v[6] = raw.w & 0xffffu; v[7] = raw.w >> 16;
        #pragma unroll
        for (int k = 0; k < 8; ++k) {
            int w = w8 + k;
            int g = (c >> 3) ^ ((w >> 3) & 7);
            tile[w * 136 + g * 8 + (c & 7)] = v[k];
        }
    }
    __syncthreads();
    #pragma unroll
    for (int i = 0; i < 8; ++i) {
        int idx = tid + 256 * i;
        int w = idx >> 4, g = idx & 15;
        int gs = g ^ ((w >> 3) & 7);
        uint4 raw = *(const uint4*)&tile[w * 136 + gs * 8];
        int c8 = g * 8;
        size_t off = (((size_t)(img * 128 + hh)) * 8 + (c8 >> 4)) * 2048 + w * 16 + (c8 & 8);
        *(uint4*)&out[off] = raw;
    }
}

// ---------------------------------------------------------------------------
// qkv MFMA v6: in-kernel x transpose (fp32 NCHW row -> 8 swizzled LDS phase
// buffers + xn global write), then BARRIER-FREE 8-phase MFMA loop (LDS is
// read-only during compute), then r16's contiguous permuted-dd epilogue.
// grid (128, 16), block 768 (12 waves = 3 w3 x {pxh x coh}).
// ---------------------------------------------------------------------------
__global__ __launch_bounds__(768, 1) void qkvm_kernel(
    const float* __restrict__ x, const ushort_t* __restrict__ Wqkv,
    const float* __restrict__ bq, const float* __restrict__ bk,
    const float* __restrict__ bv,
    ushort_t* __restrict__ xn,
    ushort_t* __restrict__ qw, ushort_t* __restrict__ kw,
    ushort_t* __restrict__ vw)
{
    // phase buffers: 8 x [128 px][16 ci swizzled] = 16384 shorts (32 KB)
    // epilogue tiles (alias, after compute): 6 x [32][136] = 26112 shorts
    __shared__ ushort_t lds[26112];
    const int h = blockIdx.x, img = blockIdx.y;
    const int tid = threadIdx.x, lane = tid & 63, wv = tid >> 6;
    const int w3 = wv >> 2, iw = wv & 3;
    const int pxh = iw & 1, coh = iw >> 1;
    const int kch = lane >> 5;
    const ushort_t* Wb = Wqkv + (size_t)w3 * 16384;
    const float* bias = (w3 == 0) ? bq : ((w3 == 1) ? bk : bv);
    const int b_ = img >> 2, t_ = img & 3;

    // 1) transpose x row h -> swizzled phase buffers (same layout staging made)
    const float* xrow = x + (size_t)img * 128 * HW_ + h * 128;
    for (int idx = tid; idx < 4096; idx += 768) {
        int c = idx >> 5, w4 = (idx & 31) * 4;
        float4 f = *(const float4*)&xrow[(size_t)c * HW_ + w4];
        int p = c >> 4, cl = c & 15, g = cl >> 3, e = cl & 7;
        ushort_t vbs[4] = { (ushort_t)f2bf(f.x), (ushort_t)f2bf(f.y),
                            (ushort_t)f2bf(f.z), (ushort_t)f2bf(f.w) };
        #pragma unroll
        for (int k = 0; k < 4; ++k) {
            int px = w4 + k;
            lds[p * 2048 + px * 16 + ((g ^ ((px >> 2) & 1)) << 3) + e] = vbs[k];
        }
    }
    __syncthreads();

    // 2) xn global write (unswizzled NHWC-p; for conv1 residual)
    for (int idx = tid; idx < 2048; idx += 768) {
        int p = idx >> 8, r = idx & 255, px = r >> 1, g = r & 1;
        uint4 raw = *(const uint4*)&lds[p * 2048 + px * 16 + ((g ^ ((px >> 2) & 1)) << 3)];
        *(uint4*)&xn[(((size_t)(img * 128 + h)) * 8 + p) * 2048 + px * 16 + g * 8] = raw;
    }

    // 3) 8-phase MFMA loop, no barriers (LDS read-only here)
    f32x16 acc[2][2];
    #pragma unroll
    for (int i = 0; i < 2; ++i)
        #pragma unroll
        for (int j = 0; j < 2; ++j)
            #pragma unroll
            for (int k = 0; k < 16; ++k) acc[i][j][k] = 0.f;

    for (int p = 0; p < 8; ++p) {
        const int fbase = p * 4 + coh * 2;
        bf16x8 wa0 = *(const bf16x8*)(Wb + ((size_t)fbase * 64 + lane) * 8);
        bf16x8 wa1 = *(const bf16x8*)(Wb + ((size_t)(fbase + 1) * 64 + lane) * 8);
        const ushort_t* bbuf = lds + p * 2048;
        #pragma unroll
        for (int i = 0; i < 2; ++i) {
            int px = pxh * 64 + i * 32 + (lane & 31);
            int s = kch ^ ((px >> 2) & 1);
            bf16x8 bv4 = *(const bf16x8*)(bbuf + px * 16 + s * 8);
            acc[i][0] = __builtin_amdgcn_mfma_f32_32x32x16_bf16(wa0, bv4, acc[i][0], 0, 0, 0);
            acc[i][1] = __builtin_amdgcn_mfma_f32_32x32x16_bf16(wa1, bv4, acc[i][1], 0, 0, 0);
        }
    }

    // 4) epilogue: per j, deposit [c_local][px] tiles, then contiguous writes
    #pragma unroll
    for (int j = 0; j < 2; ++j) {
        __syncthreads();   // all waves done reading phase buffers / prev tiles
        {
            const int scale = coh * 2 + j;
            ushort_t* tile = lds + (w3 * 2 + coh) * 4352;   // [c_local][136]
            #pragma unroll
            for (int rg = 0; rg < 16; ++rg) {
                int c_local = (rg & 3) + 8 * (rg >> 2) + 4 * kch;
                float bb = bias[scale * 32 + c_local];
                #pragma unroll
                for (int i = 0; i < 2; ++i) {
                    int px = pxh * 64 + i * 32 + (lane & 31);
                    tile[c_local * 136 + px] = (ushort_t)f2bf(acc[i][j][rg] + bb);
                }
            }
        }
        __syncthreads();
        // 3072 uint4 runs; consecutive threads -> consecutive global addresses
        #pragma unroll
        for (int l = 0; l < 4; ++l) {
            int idx = l * 768 + tid;                 // 0..3071
            int g3 = idx >> 10, rem = idx & 1023;
            int coh_t = rem >> 9, rem2 = rem & 511;
            int scale = coh_t * 2 + j;
            int lg = 6 - scale;
            int ow = rem2 >> (lg + 2);
            int rem3 = rem2 & ((1 << (lg + 2)) - 1);
            int c_local = rem3 >> (lg - 3);
            int pw0 = (rem3 & ((1 << (lg - 3)) - 1)) << 3;
            int outn = 128 >> lg;
            int Dd = 32 << (2 * lg);
            int oh = h >> lg, ph = h & ((1 << lg) - 1);
            ushort_t* outp = (g3 == 0) ? qw : ((g3 == 1) ? kw : vw);
            size_t off = (size_t)scale * 8388608u
                + ((size_t)((b_ * 4 + t_) * outn * outn + oh * outn + ow)) * (size_t)Dd
                + ((size_t)ph << (lg + 5)) + (c_local << lg) + pw0;
            uint4 raw = *(const uint4*)&lds[(g3 * 2 + coh_t) * 4352 + c_local * 136
                                            + (ow << lg) + pw0];
            *(uint4*)&outp[off] = raw;
        }
    }
}

// ---------------------------------------------------------------------------
// V transpose device body (dd-permutation agnostic).
// ---------------------------------------------------------------------------
__device__ __forceinline__ void vtrans_dev(
    const ushort_t* __restrict__ src, ushort_t* __restrict__ dst,
    int n, int Dd, int xb, int yb, int b_)
{
    const int ddb = xb * 128, tokb = yb * 128;
    const int tid = threadIdx.x;
    const int ti = tid & 15, tj = tid >> 4;
    const int tok0 = tokb + ti * 8, dd0 = ddb + tj * 8;
    if (tok0 >= n) return;
    const ushort_t* s = src + (size_t)b_ * (size_t)n * Dd;
    ushort_t* d = dst + (size_t)b_ * (size_t)n * Dd;
    ushort_t a[8][8];
    #pragma unroll
    for (int e = 0; e < 8; ++e)
        *(uint4*)a[e] = *(const uint4*)&s[(size_t)(tok0 + e) * Dd + dd0];
    #pragma unroll
    for (int q = 0; q < 8; ++q) {
        ushort_t o[8];
        #pragma unroll
        for (int e = 0; e < 8; ++e) o[e] = a[e][q];
        *(uint4*)&d[(size_t)(dd0 + q) * n + tok0] = *(uint4*)o;
    }
}

// ---------------------------------------------------------------------------
// scores, LDS-tiled (s3, s2) — unchanged.
// ---------------------------------------------------------------------------
template<int LG, int KS>
__device__ __forceinline__ void scores_lds_dev(
    const ushort_t* __restrict__ qw, const ushort_t* __restrict__ kw,
    float* __restrict__ sc_s, int bx, int by, int b_, int ks, ushort_t* lds)
{
    constexpr int outn = 128 >> LG;
    constexpr int n = 4 * outn * outn;
    constexpr int Dd = 32 << (2 * LG);
    constexpr int scale = 6 - LG;
    constexpr int DdK = Dd / KS;
    constexpr int NPH = DdK / 64;
    const size_t base = (size_t)scale * 8388608u;
    const int tid = threadIdx.x, lane = tid & 63, wv = tid >> 6;
    const ushort_t* qb = qw + base + (size_t)b_ * (size_t)n * Dd;
    const ushort_t* kb = kw + base + (size_t)b_ * (size_t)n * Dd;
    float* scb = sc_s + (size_t)b_ * n * n;
    const float scl = rsqrtf((float)Dd);
    const int mb = bx * 128, nb = by * 128;
    const int mbl = (wv & 1) * 64, nbl = (wv >> 1) * 64;
    const int k0beg = ks * DdK;

    f32x16 acc[2][2];
    #pragma unroll
    for (int i = 0; i < 2; ++i)
        #pragma unroll
        for (int j = 0; j < 2; ++j)
            #pragma unroll
            for (int k = 0; k < 16; ++k) acc[i][j][k] = 0.f;

    auto STAGE = [&](int k0, int buf) {
        #pragma unroll
        for (int l = 0; l < 4; ++l) {
            int id = l * 256 + tid;
            int row = id >> 3, ch = id & 7;
            int sw = ch ^ (row & 7);
            async16(qb + (size_t)(mb + row) * Dd + k0 + sw * 8,
                    (char*)lds + buf * 32768 + id * 16);
        }
        #pragma unroll
        for (int l = 0; l < 4; ++l) {
            int id = l * 256 + tid;
            int row = id >> 3, ch = id & 7;
            int sw = ch ^ (row & 7);
            async16(kb + (size_t)(nb + row) * Dd + k0 + sw * 8,
                    (char*)lds + buf * 32768 + 16384 + id * 16);
        }
    };

    STAGE(k0beg, 0);
    for (int p = 0; p < NPH; ++p) {
        if (p + 1 < NPH) STAGE(k0beg + (p + 1) * 64, (p + 1) & 1);
        if (p + 1 < NPH) asm volatile("s_waitcnt vmcnt(8)" ::: "memory");
        else             asm volatile("s_waitcnt vmcnt(0)" ::: "memory");
        __builtin_amdgcn_s_barrier();
        __builtin_amdgcn_s_setprio(1);
        const ushort_t* bufA = lds + (p & 1) * 16384;
        const ushort_t* bufB = bufA + 8192;
        #pragma unroll
        for (int u = 0; u < 4; ++u) {
            const int c = u * 2 + (lane >> 5);
            bf16x8 a[2], b[2];
            #pragma unroll
            for (int i = 0; i < 2; ++i) {
                int row = mbl + i * 32 + (lane & 31);
                a[i] = *(const bf16x8*)(bufA + row * 64 + ((c ^ (row & 7)) << 3));
            }
            #pragma unroll
            for (int j = 0; j < 2; ++j) {
                int row = nbl + j * 32 + (lane & 31);
                b[j] = *(const bf16x8*)(bufB + row * 64 + ((c ^ (row & 7)) << 3));
            }
            #pragma unroll
            for (int i = 0; i < 2; ++i)
                #pragma unroll
                for (int j = 0; j < 2; ++j)
                    acc[i][j] = __builtin_amdgcn_mfma_f32_32x32x16_bf16(a[i], b[j], acc[i][j], 0, 0, 0);
        }
        __builtin_amdgcn_s_setprio(0);
        __builtin_amdgcn_s_barrier();
    }

    #pragma unroll
    for (int i = 0; i < 2; ++i)
        #pragma unroll
        for (int j = 0; j < 2; ++j)
            #pragma unroll
            for (int rg = 0; rg < 16; ++rg) {
                int row = mb + mbl + i * 32 + (rg & 3) + 8 * (rg >> 2) + 4 * (lane >> 5);
                int col = nb + nbl + j * 32 + (lane & 31);
                float v = acc[i][j][rg] * scl;
                size_t off = (size_t)row * n + col;
                if (KS == 1) scb[off] = v;
                else atomicAdd(&scb[off], v);
            }
}

// ---------------------------------------------------------------------------
// scores direct body (s1 CFG1, s0 CFG2) — unchanged.
// ---------------------------------------------------------------------------
template<int CFG, int LG, int KS>
__device__ __forceinline__ void scores_dev(
    const ushort_t* __restrict__ qw, const ushort_t* __restrict__ kw,
    float* __restrict__ sc_s, int b_, int ks)
{
    constexpr int outn = 128 >> LG;
    constexpr int n = 4 * outn * outn;
    constexpr int Dd = 32 << (2 * LG);
    constexpr int scale = 6 - LG;
    constexpr int DdK = Dd / KS;
    const size_t base = (size_t)scale * 8388608u;
    const int tid = threadIdx.x, lane = tid & 63, wv = tid >> 6;
    const ushort_t* qb = qw + base + (size_t)b_ * (size_t)n * Dd;
    const ushort_t* kb = kw + base + (size_t)b_ * (size_t)n * Dd;
    float* scb = sc_s + (size_t)b_ * n * n;
    const float scl = rsqrtf((float)Dd);
    const int koff = (lane >> 5) * 8;
    const int mbq = (CFG == 1) ? (wv & 1) * 32 : 0;
    const int nbq = (CFG == 1) ? (wv >> 1) * 32 : 0;

    f32x16 acc;
    #pragma unroll
    for (int k = 0; k < 16; ++k) acc[k] = 0.f;

    int mrow = mbq + (lane & 31);
    int nrow = nbq + (lane & 31);
    if (CFG == 2) { if (mrow >= n) mrow = n - 1; if (nrow >= n) nrow = n - 1; }
    int k0beg = ks * DdK, k0end = k0beg + DdK;
    if (CFG == 2) { constexpr int DdW = DdK >> 2; k0beg += wv * DdW; k0end = k0beg + DdW; }

    for (int k0 = k0beg; k0 < k0end; k0 += 64) {
        bf16x8 a[4], b[4];
        #pragma unroll
        for (int u = 0; u < 4; ++u) {
            a[u] = *(const bf16x8*)(qb + (size_t)mrow * Dd + k0 + u * 16 + koff);
            b[u] = *(const bf16x8*)(kb + (size_t)nrow * Dd + k0 + u * 16 + koff);
        }
        #pragma unroll
        for (int u = 0; u < 4; ++u)
            acc = __builtin_amdgcn_mfma_f32_32x32x16_bf16(a[u], b[u], acc, 0, 0, 0);
    }

    #pragma unroll
    for (int rg = 0; rg < 16; ++rg) {
        int row = mbq + (rg & 3) + 8 * (rg >> 2) + 4 * (lane >> 5);
        int col = nbq + (lane & 31);
        if (CFG == 2 && (row >= n || col >= n)) continue;
        float v = acc[rg] * scl;
        size_t off = (size_t)row * n + col;
        atomicAdd(&scb[off], v);
    }
}

// fused: 1024 blocks, heavy s3 first, per-segment XCD swizzle
__global__ __launch_bounds__(256, 2) void scores_all_kernel(
    const ushort_t* __restrict__ qw, const ushort_t* __restrict__ kw,
    float* __restrict__ sc)
{
    __shared__ ushort_t slds[32768];   // 64 KB: 2 bufs x (A 16KB + B 16KB)
    const int bid = blockIdx.x;
    if (bid < 256) {                 // s3: 8x8x4, KS=1
        int l = bid;            int sid = (l & 7) * 32 + (l >> 3);
        scores_lds_dev<3, 1>(qw, kw, sc + SC_OFF3, sid & 7, (sid >> 3) & 7, sid >> 6, 0, slds);
    } else if (bid < 512) {          // s2: 2x2x4x16ks
        int l = bid - 256;      int sid = (l & 7) * 32 + (l >> 3);
        scores_lds_dev<4, 16>(qw, kw, sc + SC_OFF2, sid & 1, (sid >> 1) & 1, sid >> 6, (sid >> 2) & 15, slds);
    } else if (bid < 768) {          // s1: 4x64ks
        int l = bid - 512;      int sid = (l & 7) * 32 + (l >> 3);
        scores_dev<1, 5, 64>(qw, kw, sc + SC_OFF1, sid >> 6, sid & 63);
    } else {                         // s0: 4x64ks
        int l = bid - 768;      int sid = (l & 7) * 32 + (l >> 3);
        scores_dev<2, 6, 64>(qw, kw, sc + SC_OFF0, sid >> 6, sid & 63);
    }
}

// ---------------------------------------------------------------------------
// softmax + V-transpose fused. grid 11584 (softmax 5440, vtrans 6144).
// Legal: softmax touches sc/pbf; vtrans reads vw, writes vt(=kw region, dead
// after scores which already completed).
// ---------------------------------------------------------------------------
__global__ __launch_bounds__(256) void softmax_vtrans_kernel(
    const float* __restrict__ sc, ushort_t* __restrict__ pbf,
    const ushort_t* __restrict__ vw, ushort_t* __restrict__ vt)
{
    const int bid = blockIdx.x;
    if (bid >= 5440) {
        const int vid = bid - 5440;
        if (vid < 4096) {
            vtrans_dev(vw + 0u, vt + 0u, 16, 131072, vid & 1023, 0, vid >> 10);
        } else if (vid < 5120) {
            int sid = vid - 4096;
            vtrans_dev(vw + 8388608u, vt + 8388608u, 64, 32768, sid & 255, 0, sid >> 8);
        } else if (vid < 5632) {
            int sid = vid - 5120;
            vtrans_dev(vw + 16777216u, vt + 16777216u, 256, 8192, sid & 63, (sid >> 6) & 1, sid >> 7);
        } else {
            int sid = vid - 5632;
            vtrans_dev(vw + 25165824u, vt + 25165824u, 1024, 2048, sid & 15, (sid >> 4) & 7, sid >> 7);
        }
        return;
    }
    int n; size_t off; int row;
    if (bid < 64)        { n = 16;   row = bid;        off = SC_OFF0; }
    else if (bid < 320)  { n = 64;   row = bid - 64;   off = SC_OFF1; }
    else if (bid < 1344) { n = 256;  row = bid - 320;  off = SC_OFF2; }
    else                 { n = 1024; row = bid - 1344; off = SC_OFF3; }
    const float* p = sc + off + (size_t)row * n;
    ushort_t* q = pbf + off + (size_t)row * n;
    const int tid = threadIdx.x;
    float v[4];
    #pragma unroll
    for (int j = 0; j < 4; ++j) { int idx = tid + 256 * j; v[j] = (idx < n) ? p[idx] : -3.0e38f; }
    float m = fmaxf(fmaxf(v[0], v[1]), fmaxf(v[2], v[3]));
    #pragma unroll
    for (int off2 = 32; off2 >= 1; off2 >>= 1) m = fmaxf(m, __shfl_xor(m, off2));
    __shared__ float red[4];
    const int wid = tid >> 6, lane = tid & 63;
    if (lane == 0) red[wid] = m;
    __syncthreads();
    m = fmaxf(fmaxf(red[0], red[1]), fmaxf(red[2], red[3]));
    float e[4]; float s = 0.f;
    #pragma unroll
    for (int j = 0; j < 4; ++j) { int idx = tid + 256 * j; e[j] = (idx < n) ? __expf(v[j] - m) : 0.f; s += e[j]; }
    #pragma unroll
    for (int off2 = 32; off2 >= 1; off2 >>= 1) s += __shfl_xor(s, off2);
    __syncthreads();
    if (lane == 0) red[wid] = s;
    __syncthreads();
    s = red[0] + red[1] + red[2] + red[3];
    float inv = 1.0f / s;
    #pragma unroll
    for (int j = 0; j < 4; ++j) {
        int idx = tid + 256 * j;
        if (idx < n) q[idx] = (ushort_t)f2bf(e[j] * inv);
    }
}

// ---------------------------------------------------------------------------
// PV, LDS-tiled (s3, s2): permuted-dd decode in epilogue.
// ---------------------------------------------------------------------------
template<int LG>
__device__ __forceinline__ void pvm_lds_dev(
    const ushort_t* __restrict__ pbf_s, const ushort_t* __restrict__ vt,
    ushort_t* __restrict__ attn, int bx, int by, int b_, ushort_t* lds)
{
    constexpr int outn = 128 >> LG, psz = 1 << LG;
    constexpr int n = 4 * outn * outn;
    constexpr int Dd = 32 << (2 * LG);
    constexpr int scale = 6 - LG;
    constexpr int NPH = n / 64;
    const int tid = threadIdx.x, lane = tid & 63, wv = tid >> 6;
    const ushort_t* pb = pbf_s + (size_t)b_ * n * n;
    const ushort_t* vb = vt + (size_t)scale * 8388608u + (size_t)b_ * (size_t)Dd * n;
    const int mb = by * 128;        // tok base
    const int nb = bx * 128;        // dd base
    const int mbl = (wv & 1) * 64, nbl = (wv >> 1) * 64;

    f32x16 acc[2][2];
    #pragma unroll
    for (int i = 0; i < 2; ++i)
        #pragma unroll
        for (int j = 0; j < 2; ++j)
            #pragma unroll
            for (int k = 0; k < 16; ++k) acc[i][j][k] = 0.f;

    auto STAGE = [&](int k0, int buf) {
        #pragma unroll
        for (int l = 0; l < 4; ++l) {
            int id = l * 256 + tid;
            int row = id >> 3, ch = id & 7;
            int sw = ch ^ (row & 7);
            async16(pb + (size_t)(mb + row) * n + k0 + sw * 8,
                    (char*)lds + buf * 32768 + id * 16);
        }
        #pragma unroll
        for (int l = 0; l < 4; ++l) {
            int id = l * 256 + tid;
            int row = id >> 3, ch = id & 7;
            int sw = ch ^ (row & 7);
            async16(vb + (size_t)(nb + row) * n + k0 + sw * 8,
                    (char*)lds + buf * 32768 + 16384 + id * 16);
        }
    };

    STAGE(0, 0);
    for (int p = 0; p < NPH; ++p) {
        if (p + 1 < NPH) STAGE((p + 1) * 64, (p + 1) & 1);
        if (p + 1 < NPH) asm volatile("s_waitcnt vmcnt(8)" ::: "memory");
        else             asm volatile("s_waitcnt vmcnt(0)" ::: "memory");
        __builtin_amdgcn_s_barrier();
        __builtin_amdgcn_s_setprio(1);
        const ushort_t* bufA = lds + (p & 1) * 16384;
        const ushort_t* bufB = bufA + 8192;
        #pragma unroll
        for (int u = 0; u < 4; ++u) {
            const int c = u * 2 + (lane >> 5);
            bf16x8 a[2], b[2];
            #pragma unroll
            for (int i = 0; i < 2; ++i) {
                int row = mbl + i * 32 + (lane & 31);
                a[i] = *(const bf16x8*)(bufA + row * 64 + ((c ^ (row & 7)) << 3));
            }
            #pragma unroll
            for (int j = 0; j < 2; ++j) {
                int row = nbl + j * 32 + (lane & 31);
                b[j] = *(const bf16x8*)(bufB + row * 64 + ((c ^ (row & 7)) << 3));
            }
            #pragma unroll
            for (int i = 0; i < 2; ++i)
                #pragma unroll
                for (int j = 0; j < 2; ++j)
                    acc[i][j] = __builtin_amdgcn_mfma_f32_32x32x16_bf16(a[i], b[j], acc[i][j], 0, 0, 0);
        }
        __builtin_amdgcn_s_setprio(0);
        __builtin_amdgcn_s_barrier();
    }

    constexpr int lgo = 7 - LG;
    #pragma unroll
    for (int i = 0; i < 2; ++i)
        #pragma unroll
        for (int j = 0; j < 2; ++j)
            #pragma unroll
            for (int rg = 0; rg < 16; ++rg) {
                int tok = mb + mbl + i * 32 + (rg & 3) + 8 * (rg >> 2) + 4 * (lane >> 5);
                int dd = nb + nbl + j * 32 + (lane & 31);
                int ph = dd >> (LG + 5);
                int r2 = dd & ((1 << (LG + 5)) - 1);
                int c_local = r2 >> LG;
                int pw = r2 & (psz - 1);
                int t_ = tok >> (2 * lgo);
                int rem = tok & ((1 << (2 * lgo)) - 1);
                int oh = rem >> lgo, ow = rem & (outn - 1);
                size_t off = (((size_t)(scale * 16 + b_ * 4 + t_) * 32 + c_local) * 128
                              + ((oh << LG) + ph)) * 128 + ((ow << LG) + pw);
                attn[off] = (ushort_t)f2bf(acc[i][j][rg]);
            }
}

// ---------------------------------------------------------------------------
// PV direct body (s1 CFG1, s0 CFG2): permuted-dd decode.
// ---------------------------------------------------------------------------
template<int CFG, int LG>
__device__ __forceinline__ void pvm_dev(
    const ushort_t* __restrict__ pbf_s, const ushort_t* __restrict__ vt,
    ushort_t* __restrict__ attn, int bx, int by, int b_)
{
    constexpr int outn = 128 >> LG, psz = 1 << LG;
    constexpr int n = 4 * outn * outn;
    constexpr int Dd = 32 << (2 * LG);
    constexpr int scale = 6 - LG;
    const int tid = threadIdx.x, lane = tid & 63, wv = tid >> 6;
    const ushort_t* pb = pbf_s + (size_t)b_ * n * n;
    const ushort_t* vb = vt + (size_t)scale * 8388608u + (size_t)b_ * (size_t)Dd * n;
    const int mb = (CFG == 1) ? (wv & 1) * 32 : 0;
    const int nb = (CFG == 1) ? bx * 128 + (wv >> 1) * 64
                              : bx * 256 + wv * 64;
    const int koff = (lane >> 5) * 8;

    f32x16 acc[2];
    #pragma unroll
    for (int j = 0; j < 2; ++j)
        #pragma unroll
        for (int k = 0; k < 16; ++k) acc[j][k] = 0.f;

    int mr = mb + (lane & 31);
    if (CFG == 2 && mr >= n) mr = n - 1;
    const int nr0 = nb + (lane & 31), nr1 = nr0 + 32;

    if constexpr (CFG == 2) {
        bf16x8 b0 = *(const bf16x8*)(vb + (size_t)nr0 * n + koff);
        bf16x8 b1 = *(const bf16x8*)(vb + (size_t)nr1 * n + koff);
        bf16x8 a = *(const bf16x8*)(pb + (size_t)mr * n + koff);
        acc[0] = __builtin_amdgcn_mfma_f32_32x32x16_bf16(a, b0, acc[0], 0, 0, 0);
        acc[1] = __builtin_amdgcn_mfma_f32_32x32x16_bf16(a, b1, acc[1], 0, 0, 0);
    } else {
        for (int k0 = 0; k0 < n; k0 += 64) {
            bf16x8 vb0[4], vb1[4], pa[4];
            #pragma unroll
            for (int u = 0; u < 4; ++u) {
                vb0[u] = *(const bf16x8*)(vb + (size_t)nr0 * n + k0 + u * 16 + koff);
                vb1[u] = *(const bf16x8*)(vb + (size_t)nr1 * n + k0 + u * 16 + koff);
                pa[u]  = *(const bf16x8*)(pb + (size_t)mr * n + k0 + u * 16 + koff);
            }
            #pragma unroll
            for (int u = 0; u < 4; ++u) {
                acc[0] = __builtin_amdgcn_mfma_f32_32x32x16_bf16(pa[u], vb0[u], acc[0], 0, 0, 0);
                acc[1] = __builtin_amdgcn_mfma_f32_32x32x16_bf16(pa[u], vb1[u], acc[1], 0, 0, 0);
            }
        }
    }

    constexpr int lgo = 7 - LG;
    #pragma unroll
    for (int j = 0; j < 2; ++j)
        #pragma unroll
        for (int rg = 0; rg < 16; ++rg) {
            int tok = mb + (rg & 3) + 8 * (rg >> 2) + 4 * (lane >> 5);
            if (CFG == 2 && tok >= n) continue;
            int dd = nb + j * 32 + (lane & 31);
            int ph = dd >> (LG + 5);
            int r2 = dd & ((1 << (LG + 5)) - 1);
            int c_local = r2 >> LG;
            int pw = r2 & (psz - 1);
            int t_ = tok >> (2 * lgo);
            int rem = tok & ((1 << (2 * lgo)) - 1);
            int oh = rem >> lgo, ow = rem & (outn - 1);
            size_t off = (((size_t)(scale * 16 + b_ * 4 + t_) * 32 + c_local) * 128
                          + ((oh << LG) + ph)) * 128 + ((ow << LG) + pw);
            attn[off] = (ushort_t)f2bf(acc[j][rg]);
        }
}

// fused: 4096 blocks, heavy s3 first, per-segment XCD swizzle
__global__ __launch_bounds__(256, 2) void pvm_all_kernel(
    const ushort_t* __restrict__ pbf, const ushort_t* __restrict__ vt,
    ushort_t* __restrict__ attn)
{
    __shared__ ushort_t plds[32768];   // 64 KB: 2 bufs x (P 16KB + V 16KB)
    const int bid = blockIdx.x;
    if (bid < 512) {                 // s3: 16x8x4 (LDS-tiled)
        int l = bid;            int sid = (l & 7) * 64 + (l >> 3);
        pvm_lds_dev<3>(pbf + SC_OFF3, vt, attn, sid & 15, (sid >> 4) & 7, sid >> 7, plds);
    } else if (bid < 1024) {         // s2: 64x2x4 (LDS-tiled)
        int l = bid - 512;      int sid = (l & 7) * 64 + (l >> 3);
        pvm_lds_dev<4>(pbf + SC_OFF2, vt, attn, sid & 63, (sid >> 6) & 1, sid >> 7, plds);
    } else if (bid < 2048) {         // s1: 256x4
        int l = bid - 1024;     int sid = (l & 7) * 128 + (l >> 3);
        pvm_dev<1, 5>(pbf + SC_OFF1, vt, attn, sid & 255, 0, sid >> 8);
    } else {                         // s0: 512x4
        int l = bid - 2048;     int sid = (l & 7) * 256 + (l >> 3);
        pvm_dev<2, 6>(pbf + SC_OFF0, vt, attn, sid & 511, 0, sid >> 9);
    }
}

// ---------------------------------------------------------------------------
// MFMA implicit-GEMM 3x3 conv v5 (unchanged).
// ---------------------------------------------------------------------------
template<int DIL, int MODE>
__global__ __launch_bounds__(256, 2) void conv3x_kernel(
    const ushort_t* __restrict__ in, const ushort_t* __restrict__ Wp,
    const float* __restrict__ bias, const ushort_t* __restrict__ resn,
    float* __restrict__ outf, ushort_t* __restrict__ outn,
    const ushort_t* __restrict__ zp)
{
    __shared__ ushort_t lds[34816];
    const int fid = blockIdx.y * 64 + blockIdx.x;        // 0..1023
    const int nfid = (fid & 7) * 128 + (fid >> 3);       // XCD-bijective
    const int img = nfid >> 6, rp = nfid & 63;
    const int h0 = (DIL == 1) ? rp * 2 : ((rp & 1) + (rp >> 1) * 4);
    const int tid = threadIdx.x, lane = tid & 63, wv = tid >> 6;
    const int pxh = wv & 1, coq = wv >> 1;
    const int kch = lane >> 5;

    f32x16 acc[2][2][2];   // [row][i(px)][tn]
    #pragma unroll
    for (int r = 0; r < 2; ++r)
        #pragma unroll
        for (int i = 0; i < 2; ++i)
            #pragma unroll
            for (int j = 0; j < 2; ++j)
                #pragma unroll
                for (int k = 0; k < 16; ++k) acc[r][i][j][k] = 0.f;

    auto STAGE = [&](int p, int b) {
        #pragma unroll
        for (int kb = wv; kb < 20; kb += 4) {      // 5 loads per wave
            int slot = kb / 5, pg = kb % 5;
            int pxi = pg * 32 + (lane >> 1);
            int wc = pxi - 16;
            int ir = h0 - DIL + slot * DIL;
            int cg = (lane & 1) ^ ((pxi >> 2) & 1);
            const ushort_t* src;
            if (wc >= 0 && wc < 128 && ir >= 0 && ir < 128)
                src = in + (((size_t)(img * 128 + ir)) * 8 + p) * 2048 + wc * 16 + cg * 8;
            else
                src = zp + lane * 8;
            async16(src, (char*)lds + b * 20480 + kb * 1024);
        }
    };

    STAGE(0, 0);
    #pragma unroll
    for (int p = 0; p < 8; ++p) {
        bf16x8 w0[9], w1[9];
        #pragma unroll
        for (int tap = 0; tap < 9; ++tap) {
            int fbase = (((p >> 1) * 9 + tap) * 2 + (p & 1)) * 4 + coq * 2;
            w0[tap] = *(const bf16x8*)(Wp + ((size_t)fbase * 64 + lane) * 8);
            w1[tap] = *(const bf16x8*)(Wp + ((size_t)(fbase + 1) * 64 + lane) * 8);
        }
        asm volatile("" ::: "memory");
        if (p < 7) STAGE(p + 1, (p + 1) & 1);
        if (p < 7) asm volatile("s_waitcnt vmcnt(23)" ::: "memory");
        else       asm volatile("s_waitcnt vmcnt(18)" ::: "memory");
        __builtin_amdgcn_s_barrier();
        __builtin_amdgcn_s_setprio(1);
        const ushort_t* bbuf = lds + (p & 1) * 10240;
        #pragma unroll
        for (int tap = 0; tap < 9; ++tap) {
            const int tr = tap / 3, tc = tap % 3;
            #pragma unroll
            for (int r = 0; r < 2; ++r) {
                const ushort_t* sb = bbuf + (r + tr) * 2560;
                #pragma unroll
                for (int i = 0; i < 2; ++i) {
                    int pxi = pxh * 64 + i * 32 + (lane & 31) + (tc - 1) * DIL + 16;
                    int s = kch ^ ((pxi >> 2) & 1);
                    bf16x8 bv = *(const bf16x8*)(sb + pxi * 16 + s * 8);
                    acc[r][i][0] = __builtin_amdgcn_mfma_f32_32x32x16_bf16(w0[tap], bv, acc[r][i][0], 0, 0, 0);
                    acc[r][i][1] = __builtin_amdgcn_mfma_f32_32x32x16_bf16(w1[tap], bv, acc[r][i][1], 0, 0, 0);
                }
            }
        }
        __builtin_amdgcn_s_setprio(0);
        __builtin_amdgcn_s_barrier();
    }
    __syncthreads();

    if (MODE == 0 || MODE == 2) {
        #pragma unroll
        for (int r = 0; r < 2; ++r) {
            const int hr = h0 + r * DIL;
            for (int u = tid; u < 2048; u += 256) {
                int px = u >> 4, c8 = (u & 15) * 8;
                size_t soff = (((size_t)(img * 128 + hr)) * 8 + (c8 >> 4)) * 2048 + px * 16 + (c8 & 8);
                *(uint4*)&lds[r * 17408 + px * 136 + c8] = *(const uint4*)&resn[soff];
            }
        }
        __syncthreads();
    }
    #pragma unroll
    for (int r = 0; r < 2; ++r) {
        const int hr = h0 + r * DIL;
        #pragma unroll
        for (int i = 0; i < 2; ++i)
            #pragma unroll
            for (int tn = 0; tn < 2; ++tn)
                #pragma unroll
                for (int rgq = 0; rgq < 4; ++rgq) {
                    const int cob = coq * 64 + tn * 32 + 8 * rgq + 4 * kch;
                    const int px = pxh * 64 + i * 32 + (lane & 31);
                    float v[4];
                    #pragma unroll
                    for (int e = 0; e < 4; ++e) {
                        float t = acc[r][i][tn][rgq * 4 + e] + bias[cob + e];
                        v[e] = (t >= 0.f) ? t : 0.2f * t;
                    }
                    if (MODE == 0) {
                        uint2 rr = *(const uint2*)&lds[r * 17408 + px * 136 + cob];
                        float w0v = bf2f(rr.x & 0xffffu) + v[0];
                        float w1v = bf2f(rr.x >> 16)     + v[1];
                        float w2v = bf2f(rr.y & 0xffffu) + v[2];
                        float w3v = bf2f(rr.y >> 16)     + v[3];
                        uint2 pk;
                        pk.x = f2bf(w0v) | (f2bf(w1v) << 16);
                        pk.y = f2bf(w2v) | (f2bf(w3v) << 16);
                        *(uint2*)&lds[r * 17408 + px * 136 + cob] = pk;
                    } else if (MODE == 1) {
                        uint2 pk;
                        pk.x = f2bf(v[0]) | (f2bf(v[1]) << 16);
                        pk.y = f2bf(v[2]) | (f2bf(v[3]) << 16);
                        *(uint2*)&lds[r * 17408 + px * 136 + cob] = pk;
                    } else {
                        uint2 rr = *(const uint2*)&lds[r * 17408 + px * 136 + cob];
                        float rv[4] = { bf2f(rr.x & 0xffffu), bf2f(rr.x >> 16),
                                        bf2f(rr.y & 0xffffu), bf2f(rr.y >> 16) };
                        #pragma unroll
                        for (int e = 0; e < 4; ++e)
                            outf[(((size_t)(img * 128 + cob + e)) * 128 + hr) * 128 + px] = rv[e] + v[e];
                    }
                }
    }
    if (MODE == 0 || MODE == 1) {
        __syncthreads();
        #pragma unroll
        for (int r = 0; r < 2; ++r) {
            const int hr = h0 + r * DIL;
            for (int u = tid; u < 2048; u += 256) {
                int px = u >> 4, c8 = (u & 15) * 8;
                size_t doff = (((size_t)(img * 128 + hr)) * 8 + (c8 >> 4)) * 2048 + px * 16 + (c8 & 8);
                *(uint4*)&outn[doff] = *(const uint4*)&lds[r * 17408 + px * 136 + c8];
            }
        }
    }
}

// ---------------------------------------------------------------------------
extern "C" void kernel_launch(void* const* d_in, const int* in_sizes, int n_in,
                              void* d_out, int out_size, void* d_ws, size_t ws_size,
                              hipStream_t stream)
{
    const float* x   = (const float*)d_in[0];
    const float* Wq  = (const float*)d_in[1];
    const float* bq  = (const float*)d_in[2];
    const float* Wk  = (const float*)d_in[3];
    const float* bk  = (const float*)d_in[4];
    const float* Wv  = (const float*)d_in[5];
    const float* bv  = (const float*)d_in[6];
    const float* Wo  = (const float*)d_in[7];
    const float* bo  = (const float*)d_in[8];
    const float* Wf1 = (const float*)d_in[9];
    const float* bf1 = (const float*)d_in[10];
    const float* Wf2 = (const float*)d_in[11];
    const float* bf2 = (const float*)d_in[12];
    float* out = (float*)d_out;
    char* ws = (char*)d_ws;
    const size_t MB = 1048576ull;
    ushort_t* qw   = (ushort_t*)(ws);                 // 64 MB; attnc alias; later ff1n
    ushort_t* kw   = (ushort_t*)(ws + 64 * MB);       // 64 MB; later vt; later x1n
    ushort_t* vw   = (ushort_t*)(ws + 128 * MB);      // 64 MB; later attn NHWC-p
    ushort_t* xn   = (ushort_t*)(ws + 192 * MB);      // 64 MB; x NHWC-p (lives to conv1)
    float*    sc   = (float*)   (ws + 256 * MB);      // 17.9 MB
    ushort_t* Wp   = (ushort_t*)(ws + 274 * MB);      // 864 KB
    ushort_t* Wqkv = (ushort_t*)(ws + 275 * MB);      // 96 KB
    ushort_t* zp   = (ushort_t*)(ws + 275 * MB + 256 * 1024);  // 1 KB zeros
    ushort_t* pbf  = (ushort_t*)(ws + 276 * MB);      // 8.95 MB
    ushort_t* attnc = qw;    // attn scale-chunk NCHW (qw dead after scores)
    ushort_t* vt    = kw;    // V^T all scales (kw dead after scores)
    ushort_t* nhwc  = vw;    // attn NHWC-p (vw dead after vtrans)
    ushort_t* x1n   = kw;    // x1 NHWC-p (vt dead after pvm)
    ushort_t* ff1n  = qw;    // ff1 NHWC-p (attnc dead after attn2nhwc)

    hipMemsetAsync(zp, 0, 1024, stream);
    hipMemsetAsync(sc + SC_OFF2, 0, (size_t)(SC_TOT - SC_OFF2) * 4, stream);
    prepack_all_kernel<<<dim3(640, 3), 256, 0, stream>>>(Wo, Wf1, Wf2, Wq, Wk, Wv, Wp, Wqkv);

    // 1) fused transpose + q/k/v (writes xn for conv1 residual)
    qkvm_kernel<<<dim3(128, 16), 768, 0, stream>>>(x, Wqkv, bq, bk, bv, xn, qw, kw, vw);

    // 2) attention
    scores_all_kernel<<<dim3(1024), 256, 0, stream>>>(qw, kw, sc);
    softmax_vtrans_kernel<<<dim3(11584), 256, 0, stream>>>(sc, pbf, vw, vt);
    pvm_all_kernel<<<dim3(4096), 256, 0, stream>>>(pbf, vt, attnc);

    // 3) attn chunks -> NHWC-p (into vw region)
    attn2nhwc_kernel<<<dim3(128, 16), 256, 0, stream>>>(attnc, nhwc);
    // 4) x1 = x + lrelu(conv3x3(attn)) -> x1n NHWC-p (kw region)
    conv3x_kernel<1, 0><<<dim3(64, 16), 256, 0, stream>>>(nhwc, Wp, bo, xn, nullptr, x1n, zp);
    // 5) ff1 = lrelu(conv3x3 dil2(x1)) -> ff1n NHWC-p (qw region)
    conv3x_kernel<2, 1><<<dim3(64, 16), 256, 0, stream>>>(x1n, Wp + 147456, bf1, nullptr, nullptr, ff1n, zp);
    // 6) out = x1 + lrelu(conv3x3(ff1)) -> d_out fp32 NCHW
    conv3x_kernel<1, 2><<<dim3(64, 16), 256, 0, stream>>>(ff1n, Wp + 2 * 147456, bf2, x1n, out, nullptr, zp);
}

// Round 18
// 560.017 us; speedup vs baseline: 1.1906x; 1.0102x over previous
//
#include <hip/hip_runtime.h>
#include <stdint.h>

#define C_   128
#define H_   128
#define W_   128
#define HW_  (128*128)

// sc/pbf per-scale element offsets (s3 first, then s2, s1, s0)
#define SC_OFF3 0
#define SC_OFF2 4194304
#define SC_OFF1 4456448
#define SC_OFF0 4472832
#define SC_TOT  4473856

typedef unsigned short ushort_t;
typedef __attribute__((ext_vector_type(8)))  short bf16x8;
typedef __attribute__((ext_vector_type(16))) float f32x16;

__device__ __forceinline__ float bf2f(uint32_t u) {
    union { float f; uint32_t i; } v; v.i = u << 16; return v.f;
}
__device__ __forceinline__ uint32_t f2bf(float f) {
    union { float f; uint32_t i; } v; v.f = f;
    uint32_t u = v.i;
    uint32_t r = u + 0x7FFFu + ((u >> 16) & 1u);
    return r >> 16;  // RTNE bf16 bits in low 16
}
__device__ __forceinline__ void async16(const ushort_t* g, void* l) {
    __builtin_amdgcn_global_load_lds(
        (const __attribute__((address_space(1))) unsigned int*)g,
        (__attribute__((address_space(3))) unsigned int*)l, 16, 0, 0);
}

// NHWC-p layout: element (img, h, c, w) at ((img*128+h)*8 + (c>>4))*2048 + w*16 + (c&15)
// attn scale-chunk NCHW: ((scale*16+img)*32 + c_local)*16384 + h*128 + w (aliases qw)
// windowed layout per scale (PERMUTED dd): base = scale*8388608 +
//   (b*Ntok + tok)*Dd + dd', where dd' = ph*(32*psz) + c_local*psz + pw.
// V^T (vt, aliases kw): vt + scale*8388608 + (b*Dd + dd')*n + tok

// ---------------------------------------------------------------------------
// prepack: conv weights (bx<576) + 1x1 qkv weights (bx>=576). grid (640, 3).
// ---------------------------------------------------------------------------
__global__ __launch_bounds__(256) void prepack_all_kernel(
    const float* __restrict__ Wo, const float* __restrict__ Wf1,
    const float* __restrict__ Wf2,
    const float* __restrict__ Wq, const float* __restrict__ Wk,
    const float* __restrict__ Wv,
    ushort_t* __restrict__ Wp, ushort_t* __restrict__ Wqkv)
{
    if (blockIdx.x < 576) {
        int t = blockIdx.x * 256 + threadIdx.x;          // 0..147455
        const float* W = (blockIdx.y == 0) ? Wo : ((blockIdx.y == 1) ? Wf1 : Wf2);
        ushort_t* dst = Wp + (size_t)blockIdx.y * 147456;
        int j = t & 7, lane = (t >> 3) & 63, f = t >> 9;
        int cot = f & 3, s = (f >> 2) & 1, tap = (f >> 3) % 9, cc = f / 72;
        int co = cot * 32 + (lane & 31);
        int ci = cc * 32 + s * 16 + (lane >> 5) * 8 + j;
        dst[t] = (ushort_t)f2bf(W[((size_t)co * 128 + ci) * 9 + tap]);
    } else {
        int t = (blockIdx.x - 576) * 256 + threadIdx.x;  // 0..16383
        const float* W = (blockIdx.y == 0) ? Wq : ((blockIdx.y == 1) ? Wk : Wv);
        ushort_t* dst = Wqkv + (size_t)blockIdx.y * 16384;
        int j = t & 7, lane = (t >> 3) & 63, f = t >> 9;  // f 0..31
        int cot = f & 3, s = f >> 2;
        int co = cot * 32 + (lane & 31);
        int ci = s * 16 + (lane >> 5) * 8 + j;
        dst[t] = (ushort_t)f2bf(W[(size_t)co * 128 + ci]);
    }
}

// ---------------------------------------------------------------------------
// attn scale-chunk NCHW (bf16) -> NHWC-p bf16. grid (128, 16).
// ---------------------------------------------------------------------------
__global__ __launch_bounds__(256) void attn2nhwc_kernel(
    const ushort_t* __restrict__ in, ushort_t* __restrict__ out)
{
    __shared__ ushort_t tile[128 * 136];
    const int img = blockIdx.y, hh = blockIdx.x;
    const int tid = threadIdx.x;
    #pragma unroll
    for (int i = 0; i < 8; ++i) {
        int idx = tid + 256 * i;
        int c = idx >> 4, w8 = (idx & 15) * 8;
        size_t src = (((size_t)((c >> 5) * 16 + img)) * 32 + (c & 31)) * (size_t)HW_
                     + hh * 128 + w8;
        uint4 raw = *(const uint4*)&in[src];
        ushort_t v[8];
        v[0] = raw.x & 0xffffu; v[1] = raw.x >> 16;
        v[2] = raw.y & 0xffffu; v[3] = raw.y >> 16;
        v[4] = raw.z & 0xffffu; v[5] = raw.z >> 16;
        v[6] = raw.w & 0xffffu; v[7] = raw.w >> 16;
        #pragma unroll
        for (int k = 0; k < 8; ++k) {
            int w = w8 + k;
            int g = (c >> 3) ^ ((w >> 3) & 7);
            tile[w * 136 + g * 8 + (c & 7)] = v[k];
        }
    }
    __syncthreads();
    #pragma unroll
    for (int i = 0; i < 8; ++i) {
        int idx = tid + 256 * i;
        int w = idx >> 4, g = idx & 15;
        int gs = g ^ ((w >> 3) & 7);
        uint4 raw = *(const uint4*)&tile[w * 136 + gs * 8];
        int c8 = g * 8;
        size_t off = (((size_t)(img * 128 + hh)) * 8 + (c8 >> 4)) * 2048 + w * 16 + (c8 & 8);
        *(uint4*)&out[off] = raw;
    }
}

// ---------------------------------------------------------------------------
// qkv MFMA v7: in-kernel x transpose via GATHER-8 (one vector LDS write per
// 16-byte chunk -> no 32-way write conflicts), xn global write, BARRIER-FREE
// 8-phase MFMA loop, contiguous permuted-dd epilogue.
// grid (128, 16), block 768 (12 waves = 3 w3 x {pxh x coh}).
// ---------------------------------------------------------------------------
__global__ __launch_bounds__(768, 1) void qkvm_kernel(
    const float* __restrict__ x, const ushort_t* __restrict__ Wqkv,
    const float* __restrict__ bq, const float* __restrict__ bk,
    const float* __restrict__ bv,
    ushort_t* __restrict__ xn,
    ushort_t* __restrict__ qw, ushort_t* __restrict__ kw,
    ushort_t* __restrict__ vw)
{
    // phase buffers: 8 x [128 px][16 ci swizzled] = 16384 shorts (32 KB)
    // epilogue tiles (alias, after compute): 6 x [32][136] = 26112 shorts
    __shared__ ushort_t lds[26112];
    const int h = blockIdx.x, img = blockIdx.y;
    const int tid = threadIdx.x, lane = tid & 63, wv = tid >> 6;
    const int w3 = wv >> 2, iw = wv & 3;
    const int pxh = iw & 1, coh = iw >> 1;
    const int kch = lane >> 5;
    const ushort_t* Wb = Wqkv + (size_t)w3 * 16384;
    const float* bias = (w3 == 0) ? bq : ((w3 == 1) ? bk : bv);
    const int b_ = img >> 2, t_ = img & 3;

    // 1) transpose x row h: each thread gathers 8 channels of one (p,g,px)
    //    chunk and emits ONE uint4 LDS write (4-way max, no 32-way conflicts)
    const float* xrow = x + (size_t)img * 128 * HW_ + h * 128;
    for (int idx = tid; idx < 2048; idx += 768) {
        int px = idx & 127, pg = idx >> 7;       // pg 0..15
        int p = pg >> 1, g = pg & 1;
        int cb = p * 16 + g * 8;
        ushort_t vbs[8];
        #pragma unroll
        for (int e = 0; e < 8; ++e)
            vbs[e] = (ushort_t)f2bf(xrow[(size_t)(cb + e) * HW_ + px]);
        *(uint4*)&lds[p * 2048 + px * 16 + ((g ^ ((px >> 2) & 1)) << 3)] = *(uint4*)vbs;
    }
    __syncthreads();

    // 2) xn global write (unswizzled NHWC-p; for conv1 residual)
    for (int idx = tid; idx < 2048; idx += 768) {
        int p = idx >> 8, r = idx & 255, px = r >> 1, g = r & 1;
        uint4 raw = *(const uint4*)&lds[p * 2048 + px * 16 + ((g ^ ((px >> 2) & 1)) << 3)];
        *(uint4*)&xn[(((size_t)(img * 128 + h)) * 8 + p) * 2048 + px * 16 + g * 8] = raw;
    }

    // 3) 8-phase MFMA loop, no barriers (LDS read-only here)
    f32x16 acc[2][2];
    #pragma unroll
    for (int i = 0; i < 2; ++i)
        #pragma unroll
        for (int j = 0; j < 2; ++j)
            #pragma unroll
            for (int k = 0; k < 16; ++k) acc[i][j][k] = 0.f;

    for (int p = 0; p < 8; ++p) {
        const int fbase = p * 4 + coh * 2;
        bf16x8 wa0 = *(const bf16x8*)(Wb + ((size_t)fbase * 64 + lane) * 8);
        bf16x8 wa1 = *(const bf16x8*)(Wb + ((size_t)(fbase + 1) * 64 + lane) * 8);
        const ushort_t* bbuf = lds + p * 2048;
        #pragma unroll
        for (int i = 0; i < 2; ++i) {
            int px = pxh * 64 + i * 32 + (lane & 31);
            int s = kch ^ ((px >> 2) & 1);
            bf16x8 bv4 = *(const bf16x8*)(bbuf + px * 16 + s * 8);
            acc[i][0] = __builtin_amdgcn_mfma_f32_32x32x16_bf16(wa0, bv4, acc[i][0], 0, 0, 0);
            acc[i][1] = __builtin_amdgcn_mfma_f32_32x32x16_bf16(wa1, bv4, acc[i][1], 0, 0, 0);
        }
    }

    // 4) epilogue: per j, deposit [c_local][px] tiles, then contiguous writes
    #pragma unroll
    for (int j = 0; j < 2; ++j) {
        __syncthreads();   // all waves done reading phase buffers / prev tiles
        {
            const int scale = coh * 2 + j;
            ushort_t* tile = lds + (w3 * 2 + coh) * 4352;   // [c_local][136]
            #pragma unroll
            for (int rg = 0; rg < 16; ++rg) {
                int c_local = (rg & 3) + 8 * (rg >> 2) + 4 * kch;
                float bb = bias[scale * 32 + c_local];
                #pragma unroll
                for (int i = 0; i < 2; ++i) {
                    int px = pxh * 64 + i * 32 + (lane & 31);
                    tile[c_local * 136 + px] = (ushort_t)f2bf(acc[i][j][rg] + bb);
                }
            }
        }
        __syncthreads();
        // 3072 uint4 runs; consecutive threads -> consecutive global addresses
        #pragma unroll
        for (int l = 0; l < 4; ++l) {
            int idx = l * 768 + tid;                 // 0..3071
            int g3 = idx >> 10, rem = idx & 1023;
            int coh_t = rem >> 9, rem2 = rem & 511;
            int scale = coh_t * 2 + j;
            int lg = 6 - scale;
            int ow = rem2 >> (lg + 2);
            int rem3 = rem2 & ((1 << (lg + 2)) - 1);
            int c_local = rem3 >> (lg - 3);
            int pw0 = (rem3 & ((1 << (lg - 3)) - 1)) << 3;
            int outn = 128 >> lg;
            int Dd = 32 << (2 * lg);
            int oh = h >> lg, ph = h & ((1 << lg) - 1);
            ushort_t* outp = (g3 == 0) ? qw : ((g3 == 1) ? kw : vw);
            size_t off = (size_t)scale * 8388608u
                + ((size_t)((b_ * 4 + t_) * outn * outn + oh * outn + ow)) * (size_t)Dd
                + ((size_t)ph << (lg + 5)) + (c_local << lg) + pw0;
            uint4 raw = *(const uint4*)&lds[(g3 * 2 + coh_t) * 4352 + c_local * 136
                                            + (ow << lg) + pw0];
            *(uint4*)&outp[off] = raw;
        }
    }
}

// ---------------------------------------------------------------------------
// V transpose device body (dd-permutation agnostic).
// ---------------------------------------------------------------------------
__device__ __forceinline__ void vtrans_dev(
    const ushort_t* __restrict__ src, ushort_t* __restrict__ dst,
    int n, int Dd, int xb, int yb, int b_)
{
    const int ddb = xb * 128, tokb = yb * 128;
    const int tid = threadIdx.x;
    const int ti = tid & 15, tj = tid >> 4;
    const int tok0 = tokb + ti * 8, dd0 = ddb + tj * 8;
    if (tok0 >= n) return;
    const ushort_t* s = src + (size_t)b_ * (size_t)n * Dd;
    ushort_t* d = dst + (size_t)b_ * (size_t)n * Dd;
    ushort_t a[8][8];
    #pragma unroll
    for (int e = 0; e < 8; ++e)
        *(uint4*)a[e] = *(const uint4*)&s[(size_t)(tok0 + e) * Dd + dd0];
    #pragma unroll
    for (int q = 0; q < 8; ++q) {
        ushort_t o[8];
        #pragma unroll
        for (int e = 0; e < 8; ++e) o[e] = a[e][q];
        *(uint4*)&d[(size_t)(dd0 + q) * n + tok0] = *(uint4*)o;
    }
}

// ---------------------------------------------------------------------------
// scores, LDS-tiled (s3, s2) — unchanged.
// ---------------------------------------------------------------------------
template<int LG, int KS>
__device__ __forceinline__ void scores_lds_dev(
    const ushort_t* __restrict__ qw, const ushort_t* __restrict__ kw,
    float* __restrict__ sc_s, int bx, int by, int b_, int ks, ushort_t* lds)
{
    constexpr int outn = 128 >> LG;
    constexpr int n = 4 * outn * outn;
    constexpr int Dd = 32 << (2 * LG);
    constexpr int scale = 6 - LG;
    constexpr int DdK = Dd / KS;
    constexpr int NPH = DdK / 64;
    const size_t base = (size_t)scale * 8388608u;
    const int tid = threadIdx.x, lane = tid & 63, wv = tid >> 6;
    const ushort_t* qb = qw + base + (size_t)b_ * (size_t)n * Dd;
    const ushort_t* kb = kw + base + (size_t)b_ * (size_t)n * Dd;
    float* scb = sc_s + (size_t)b_ * n * n;
    const float scl = rsqrtf((float)Dd);
    const int mb = bx * 128, nb = by * 128;
    const int mbl = (wv & 1) * 64, nbl = (wv >> 1) * 64;
    const int k0beg = ks * DdK;

    f32x16 acc[2][2];
    #pragma unroll
    for (int i = 0; i < 2; ++i)
        #pragma unroll
        for (int j = 0; j < 2; ++j)
            #pragma unroll
            for (int k = 0; k < 16; ++k) acc[i][j][k] = 0.f;

    auto STAGE = [&](int k0, int buf) {
        #pragma unroll
        for (int l = 0; l < 4; ++l) {
            int id = l * 256 + tid;
            int row = id >> 3, ch = id & 7;
            int sw = ch ^ (row & 7);
            async16(qb + (size_t)(mb + row) * Dd + k0 + sw * 8,
                    (char*)lds + buf * 32768 + id * 16);
        }
        #pragma unroll
        for (int l = 0; l < 4; ++l) {
            int id = l * 256 + tid;
            int row = id >> 3, ch = id & 7;
            int sw = ch ^ (row & 7);
            async16(kb + (size_t)(nb + row) * Dd + k0 + sw * 8,
                    (char*)lds + buf * 32768 + 16384 + id * 16);
        }
    };

    STAGE(k0beg, 0);
    for (int p = 0; p < NPH; ++p) {
        if (p + 1 < NPH) STAGE(k0beg + (p + 1) * 64, (p + 1) & 1);
        if (p + 1 < NPH) asm volatile("s_waitcnt vmcnt(8)" ::: "memory");
        else             asm volatile("s_waitcnt vmcnt(0)" ::: "memory");
        __builtin_amdgcn_s_barrier();
        __builtin_amdgcn_s_setprio(1);
        const ushort_t* bufA = lds + (p & 1) * 16384;
        const ushort_t* bufB = bufA + 8192;
        #pragma unroll
        for (int u = 0; u < 4; ++u) {
            const int c = u * 2 + (lane >> 5);
            bf16x8 a[2], b[2];
            #pragma unroll
            for (int i = 0; i < 2; ++i) {
                int row = mbl + i * 32 + (lane & 31);
                a[i] = *(const bf16x8*)(bufA + row * 64 + ((c ^ (row & 7)) << 3));
            }
            #pragma unroll
            for (int j = 0; j < 2; ++j) {
                int row = nbl + j * 32 + (lane & 31);
                b[j] = *(const bf16x8*)(bufB + row * 64 + ((c ^ (row & 7)) << 3));
            }
            #pragma unroll
            for (int i = 0; i < 2; ++i)
                #pragma unroll
                for (int j = 0; j < 2; ++j)
                    acc[i][j] = __builtin_amdgcn_mfma_f32_32x32x16_bf16(a[i], b[j], acc[i][j], 0, 0, 0);
        }
        __builtin_amdgcn_s_setprio(0);
        __builtin_amdgcn_s_barrier();
    }

    #pragma unroll
    for (int i = 0; i < 2; ++i)
        #pragma unroll
        for (int j = 0; j < 2; ++j)
            #pragma unroll
            for (int rg = 0; rg < 16; ++rg) {
                int row = mb + mbl + i * 32 + (rg & 3) + 8 * (rg >> 2) + 4 * (lane >> 5);
                int col = nb + nbl + j * 32 + (lane & 31);
                float v = acc[i][j][rg] * scl;
                size_t off = (size_t)row * n + col;
                if (KS == 1) scb[off] = v;
                else atomicAdd(&scb[off], v);
            }
}

// ---------------------------------------------------------------------------
// scores direct body (s1 CFG1, s0 CFG2) — unchanged.
// ---------------------------------------------------------------------------
template<int CFG, int LG, int KS>
__device__ __forceinline__ void scores_dev(
    const ushort_t* __restrict__ qw, const ushort_t* __restrict__ kw,
    float* __restrict__ sc_s, int b_, int ks)
{
    constexpr int outn = 128 >> LG;
    constexpr int n = 4 * outn * outn;
    constexpr int Dd = 32 << (2 * LG);
    constexpr int scale = 6 - LG;
    constexpr int DdK = Dd / KS;
    const size_t base = (size_t)scale * 8388608u;
    const int tid = threadIdx.x, lane = tid & 63, wv = tid >> 6;
    const ushort_t* qb = qw + base + (size_t)b_ * (size_t)n * Dd;
    const ushort_t* kb = kw + base + (size_t)b_ * (size_t)n * Dd;
    float* scb = sc_s + (size_t)b_ * n * n;
    const float scl = rsqrtf((float)Dd);
    const int koff = (lane >> 5) * 8;
    const int mbq = (CFG == 1) ? (wv & 1) * 32 : 0;
    const int nbq = (CFG == 1) ? (wv >> 1) * 32 : 0;

    f32x16 acc;
    #pragma unroll
    for (int k = 0; k < 16; ++k) acc[k] = 0.f;

    int mrow = mbq + (lane & 31);
    int nrow = nbq + (lane & 31);
    if (CFG == 2) { if (mrow >= n) mrow = n - 1; if (nrow >= n) nrow = n - 1; }
    int k0beg = ks * DdK, k0end = k0beg + DdK;
    if (CFG == 2) { constexpr int DdW = DdK >> 2; k0beg += wv * DdW; k0end = k0beg + DdW; }

    for (int k0 = k0beg; k0 < k0end; k0 += 64) {
        bf16x8 a[4], b[4];
        #pragma unroll
        for (int u = 0; u < 4; ++u) {
            a[u] = *(const bf16x8*)(qb + (size_t)mrow * Dd + k0 + u * 16 + koff);
            b[u] = *(const bf16x8*)(kb + (size_t)nrow * Dd + k0 + u * 16 + koff);
        }
        #pragma unroll
        for (int u = 0; u < 4; ++u)
            acc = __builtin_amdgcn_mfma_f32_32x32x16_bf16(a[u], b[u], acc, 0, 0, 0);
    }

    #pragma unroll
    for (int rg = 0; rg < 16; ++rg) {
        int row = mbq + (rg & 3) + 8 * (rg >> 2) + 4 * (lane >> 5);
        int col = nbq + (lane & 31);
        if (CFG == 2 && (row >= n || col >= n)) continue;
        float v = acc[rg] * scl;
        size_t off = (size_t)row * n + col;
        atomicAdd(&scb[off], v);
    }
}

// fused: 1024 blocks, heavy s3 first, per-segment XCD swizzle
__global__ __launch_bounds__(256, 2) void scores_all_kernel(
    const ushort_t* __restrict__ qw, const ushort_t* __restrict__ kw,
    float* __restrict__ sc)
{
    __shared__ ushort_t slds[32768];   // 64 KB: 2 bufs x (A 16KB + B 16KB)
    const int bid = blockIdx.x;
    if (bid < 256) {                 // s3: 8x8x4, KS=1
        int l = bid;            int sid = (l & 7) * 32 + (l >> 3);
        scores_lds_dev<3, 1>(qw, kw, sc + SC_OFF3, sid & 7, (sid >> 3) & 7, sid >> 6, 0, slds);
    } else if (bid < 512) {          // s2: 2x2x4x16ks
        int l = bid - 256;      int sid = (l & 7) * 32 + (l >> 3);
        scores_lds_dev<4, 16>(qw, kw, sc + SC_OFF2, sid & 1, (sid >> 1) & 1, sid >> 6, (sid >> 2) & 15, slds);
    } else if (bid < 768) {          // s1: 4x64ks
        int l = bid - 512;      int sid = (l & 7) * 32 + (l >> 3);
        scores_dev<1, 5, 64>(qw, kw, sc + SC_OFF1, sid >> 6, sid & 63);
    } else {                         // s0: 4x64ks
        int l = bid - 768;      int sid = (l & 7) * 32 + (l >> 3);
        scores_dev<2, 6, 64>(qw, kw, sc + SC_OFF0, sid >> 6, sid & 63);
    }
}

// ---------------------------------------------------------------------------
// softmax + V-transpose fused. grid 11584 (softmax 5440, vtrans 6144).
// ---------------------------------------------------------------------------
__global__ __launch_bounds__(256) void softmax_vtrans_kernel(
    const float* __restrict__ sc, ushort_t* __restrict__ pbf,
    const ushort_t* __restrict__ vw, ushort_t* __restrict__ vt)
{
    const int bid = blockIdx.x;
    if (bid >= 5440) {
        const int vid = bid - 5440;
        if (vid < 4096) {
            vtrans_dev(vw + 0u, vt + 0u, 16, 131072, vid & 1023, 0, vid >> 10);
        } else if (vid < 5120) {
            int sid = vid - 4096;
            vtrans_dev(vw + 8388608u, vt + 8388608u, 64, 32768, sid & 255, 0, sid >> 8);
        } else if (vid < 5632) {
            int sid = vid - 5120;
            vtrans_dev(vw + 16777216u, vt + 16777216u, 256, 8192, sid & 63, (sid >> 6) & 1, sid >> 7);
        } else {
            int sid = vid - 5632;
            vtrans_dev(vw + 25165824u, vt + 25165824u, 1024, 2048, sid & 15, (sid >> 4) & 7, sid >> 7);
        }
        return;
    }
    int n; size_t off; int row;
    if (bid < 64)        { n = 16;   row = bid;        off = SC_OFF0; }
    else if (bid < 320)  { n = 64;   row = bid - 64;   off = SC_OFF1; }
    else if (bid < 1344) { n = 256;  row = bid - 320;  off = SC_OFF2; }
    else                 { n = 1024; row = bid - 1344; off = SC_OFF3; }
    const float* p = sc + off + (size_t)row * n;
    ushort_t* q = pbf + off + (size_t)row * n;
    const int tid = threadIdx.x;
    float v[4];
    #pragma unroll
    for (int j = 0; j < 4; ++j) { int idx = tid + 256 * j; v[j] = (idx < n) ? p[idx] : -3.0e38f; }
    float m = fmaxf(fmaxf(v[0], v[1]), fmaxf(v[2], v[3]));
    #pragma unroll
    for (int off2 = 32; off2 >= 1; off2 >>= 1) m = fmaxf(m, __shfl_xor(m, off2));
    __shared__ float red[4];
    const int wid = tid >> 6, lane = tid & 63;
    if (lane == 0) red[wid] = m;
    __syncthreads();
    m = fmaxf(fmaxf(red[0], red[1]), fmaxf(red[2], red[3]));
    float e[4]; float s = 0.f;
    #pragma unroll
    for (int j = 0; j < 4; ++j) { int idx = tid + 256 * j; e[j] = (idx < n) ? __expf(v[j] - m) : 0.f; s += e[j]; }
    #pragma unroll
    for (int off2 = 32; off2 >= 1; off2 >>= 1) s += __shfl_xor(s, off2);
    __syncthreads();
    if (lane == 0) red[wid] = s;
    __syncthreads();
    s = red[0] + red[1] + red[2] + red[3];
    float inv = 1.0f / s;
    #pragma unroll
    for (int j = 0; j < 4; ++j) {
        int idx = tid + 256 * j;
        if (idx < n) q[idx] = (ushort_t)f2bf(e[j] * inv);
    }
}

// ---------------------------------------------------------------------------
// PV, LDS-tiled (s3, s2): permuted-dd decode in epilogue.
// ---------------------------------------------------------------------------
template<int LG>
__device__ __forceinline__ void pvm_lds_dev(
    const ushort_t* __restrict__ pbf_s, const ushort_t* __restrict__ vt,
    ushort_t* __restrict__ attn, int bx, int by, int b_, ushort_t* lds)
{
    constexpr int outn = 128 >> LG, psz = 1 << LG;
    constexpr int n = 4 * outn * outn;
    constexpr int Dd = 32 << (2 * LG);
    constexpr int scale = 6 - LG;
    constexpr int NPH = n / 64;
    const int tid = threadIdx.x, lane = tid & 63, wv = tid >> 6;
    const ushort_t* pb = pbf_s + (size_t)b_ * n * n;
    const ushort_t* vb = vt + (size_t)scale * 8388608u + (size_t)b_ * (size_t)Dd * n;
    const int mb = by * 128;        // tok base
    const int nb = bx * 128;        // dd base
    const int mbl = (wv & 1) * 64, nbl = (wv >> 1) * 64;

    f32x16 acc[2][2];
    #pragma unroll
    for (int i = 0; i < 2; ++i)
        #pragma unroll
        for (int j = 0; j < 2; ++j)
            #pragma unroll
            for (int k = 0; k < 16; ++k) acc[i][j][k] = 0.f;

    auto STAGE = [&](int k0, int buf) {
        #pragma unroll
        for (int l = 0; l < 4; ++l) {
            int id = l * 256 + tid;
            int row = id >> 3, ch = id & 7;
            int sw = ch ^ (row & 7);
            async16(pb + (size_t)(mb + row) * n + k0 + sw * 8,
                    (char*)lds + buf * 32768 + id * 16);
        }
        #pragma unroll
        for (int l = 0; l < 4; ++l) {
            int id = l * 256 + tid;
            int row = id >> 3, ch = id & 7;
            int sw = ch ^ (row & 7);
            async16(vb + (size_t)(nb + row) * n + k0 + sw * 8,
                    (char*)lds + buf * 32768 + 16384 + id * 16);
        }
    };

    STAGE(0, 0);
    for (int p = 0; p < NPH; ++p) {
        if (p + 1 < NPH) STAGE((p + 1) * 64, (p + 1) & 1);
        if (p + 1 < NPH) asm volatile("s_waitcnt vmcnt(8)" ::: "memory");
        else             asm volatile("s_waitcnt vmcnt(0)" ::: "memory");
        __builtin_amdgcn_s_barrier();
        __builtin_amdgcn_s_setprio(1);
        const ushort_t* bufA = lds + (p & 1) * 16384;
        const ushort_t* bufB = bufA + 8192;
        #pragma unroll
        for (int u = 0; u < 4; ++u) {
            const int c = u * 2 + (lane >> 5);
            bf16x8 a[2], b[2];
            #pragma unroll
            for (int i = 0; i < 2; ++i) {
                int row = mbl + i * 32 + (lane & 31);
                a[i] = *(const bf16x8*)(bufA + row * 64 + ((c ^ (row & 7)) << 3));
            }
            #pragma unroll
            for (int j = 0; j < 2; ++j) {
                int row = nbl + j * 32 + (lane & 31);
                b[j] = *(const bf16x8*)(bufB + row * 64 + ((c ^ (row & 7)) << 3));
            }
            #pragma unroll
            for (int i = 0; i < 2; ++i)
                #pragma unroll
                for (int j = 0; j < 2; ++j)
                    acc[i][j] = __builtin_amdgcn_mfma_f32_32x32x16_bf16(a[i], b[j], acc[i][j], 0, 0, 0);
        }
        __builtin_amdgcn_s_setprio(0);
        __builtin_amdgcn_s_barrier();
    }

    constexpr int lgo = 7 - LG;
    #pragma unroll
    for (int i = 0; i < 2; ++i)
        #pragma unroll
        for (int j = 0; j < 2; ++j)
            #pragma unroll
            for (int rg = 0; rg < 16; ++rg) {
                int tok = mb + mbl + i * 32 + (rg & 3) + 8 * (rg >> 2) + 4 * (lane >> 5);
                int dd = nb + nbl + j * 32 + (lane & 31);
                int ph = dd >> (LG + 5);
                int r2 = dd & ((1 << (LG + 5)) - 1);
                int c_local = r2 >> LG;
                int pw = r2 & (psz - 1);
                int t_ = tok >> (2 * lgo);
                int rem = tok & ((1 << (2 * lgo)) - 1);
                int oh = rem >> lgo, ow = rem & (outn - 1);
                size_t off = (((size_t)(scale * 16 + b_ * 4 + t_) * 32 + c_local) * 128
                              + ((oh << LG) + ph)) * 128 + ((ow << LG) + pw);
                attn[off] = (ushort_t)f2bf(acc[i][j][rg]);
            }
}

// ---------------------------------------------------------------------------
// PV direct body (s1 CFG1, s0 CFG2): permuted-dd decode.
// ---------------------------------------------------------------------------
template<int CFG, int LG>
__device__ __forceinline__ void pvm_dev(
    const ushort_t* __restrict__ pbf_s, const ushort_t* __restrict__ vt,
    ushort_t* __restrict__ attn, int bx, int by, int b_)
{
    constexpr int outn = 128 >> LG, psz = 1 << LG;
    constexpr int n = 4 * outn * outn;
    constexpr int Dd = 32 << (2 * LG);
    constexpr int scale = 6 - LG;
    const int tid = threadIdx.x, lane = tid & 63, wv = tid >> 6;
    const ushort_t* pb = pbf_s + (size_t)b_ * n * n;
    const ushort_t* vb = vt + (size_t)scale * 8388608u + (size_t)b_ * (size_t)Dd * n;
    const int mb = (CFG == 1) ? (wv & 1) * 32 : 0;
    const int nb = (CFG == 1) ? bx * 128 + (wv >> 1) * 64
                              : bx * 256 + wv * 64;
    const int koff = (lane >> 5) * 8;

    f32x16 acc[2];
    #pragma unroll
    for (int j = 0; j < 2; ++j)
        #pragma unroll
        for (int k = 0; k < 16; ++k) acc[j][k] = 0.f;

    int mr = mb + (lane & 31);
    if (CFG == 2 && mr >= n) mr = n - 1;
    const int nr0 = nb + (lane & 31), nr1 = nr0 + 32;

    if constexpr (CFG == 2) {
        bf16x8 b0 = *(const bf16x8*)(vb + (size_t)nr0 * n + koff);
        bf16x8 b1 = *(const bf16x8*)(vb + (size_t)nr1 * n + koff);
        bf16x8 a = *(const bf16x8*)(pb + (size_t)mr * n + koff);
        acc[0] = __builtin_amdgcn_mfma_f32_32x32x16_bf16(a, b0, acc[0], 0, 0, 0);
        acc[1] = __builtin_amdgcn_mfma_f32_32x32x16_bf16(a, b1, acc[1], 0, 0, 0);
    } else {
        for (int k0 = 0; k0 < n; k0 += 64) {
            bf16x8 vb0[4], vb1[4], pa[4];
            #pragma unroll
            for (int u = 0; u < 4; ++u) {
                vb0[u] = *(const bf16x8*)(vb + (size_t)nr0 * n + k0 + u * 16 + koff);
                vb1[u] = *(const bf16x8*)(vb + (size_t)nr1 * n + k0 + u * 16 + koff);
                pa[u]  = *(const bf16x8*)(pb + (size_t)mr * n + k0 + u * 16 + koff);
            }
            #pragma unroll
            for (int u = 0; u < 4; ++u) {
                acc[0] = __builtin_amdgcn_mfma_f32_32x32x16_bf16(pa[u], vb0[u], acc[0], 0, 0, 0);
                acc[1] = __builtin_amdgcn_mfma_f32_32x32x16_bf16(pa[u], vb1[u], acc[1], 0, 0, 0);
            }
        }
    }

    constexpr int lgo = 7 - LG;
    #pragma unroll
    for (int j = 0; j < 2; ++j)
        #pragma unroll
        for (int rg = 0; rg < 16; ++rg) {
            int tok = mb + (rg & 3) + 8 * (rg >> 2) + 4 * (lane >> 5);
            if (CFG == 2 && tok >= n) continue;
            int dd = nb + j * 32 + (lane & 31);
            int ph = dd >> (LG + 5);
            int r2 = dd & ((1 << (LG + 5)) - 1);
            int c_local = r2 >> LG;
            int pw = r2 & (psz - 1);
            int t_ = tok >> (2 * lgo);
            int rem = tok & ((1 << (2 * lgo)) - 1);
            int oh = rem >> lgo, ow = rem & (outn - 1);
            size_t off = (((size_t)(scale * 16 + b_ * 4 + t_) * 32 + c_local) * 128
                          + ((oh << LG) + ph)) * 128 + ((ow << LG) + pw);
            attn[off] = (ushort_t)f2bf(acc[j][rg]);
        }
}

// fused: 4096 blocks, heavy s3 first, per-segment XCD swizzle
__global__ __launch_bounds__(256, 2) void pvm_all_kernel(
    const ushort_t* __restrict__ pbf, const ushort_t* __restrict__ vt,
    ushort_t* __restrict__ attn)
{
    __shared__ ushort_t plds[32768];   // 64 KB: 2 bufs x (P 16KB + V 16KB)
    const int bid = blockIdx.x;
    if (bid < 512) {                 // s3: 16x8x4 (LDS-tiled)
        int l = bid;            int sid = (l & 7) * 64 + (l >> 3);
        pvm_lds_dev<3>(pbf + SC_OFF3, vt, attn, sid & 15, (sid >> 4) & 7, sid >> 7, plds);
    } else if (bid < 1024) {         // s2: 64x2x4 (LDS-tiled)
        int l = bid - 512;      int sid = (l & 7) * 64 + (l >> 3);
        pvm_lds_dev<4>(pbf + SC_OFF2, vt, attn, sid & 63, (sid >> 6) & 1, sid >> 7, plds);
    } else if (bid < 2048) {         // s1: 256x4
        int l = bid - 1024;     int sid = (l & 7) * 128 + (l >> 3);
        pvm_dev<1, 5>(pbf + SC_OFF1, vt, attn, sid & 255, 0, sid >> 8);
    } else {                         // s0: 512x4
        int l = bid - 2048;     int sid = (l & 7) * 256 + (l >> 3);
        pvm_dev<2, 6>(pbf + SC_OFF0, vt, attn, sid & 511, 0, sid >> 9);
    }
}

// ---------------------------------------------------------------------------
// MFMA implicit-GEMM 3x3 conv v5 (unchanged).
// ---------------------------------------------------------------------------
template<int DIL, int MODE>
__global__ __launch_bounds__(256, 2) void conv3x_kernel(
    const ushort_t* __restrict__ in, const ushort_t* __restrict__ Wp,
    const float* __restrict__ bias, const ushort_t* __restrict__ resn,
    float* __restrict__ outf, ushort_t* __restrict__ outn,
    const ushort_t* __restrict__ zp)
{
    __shared__ ushort_t lds[34816];
    const int fid = blockIdx.y * 64 + blockIdx.x;        // 0..1023
    const int nfid = (fid & 7) * 128 + (fid >> 3);       // XCD-bijective
    const int img = nfid >> 6, rp = nfid & 63;
    const int h0 = (DIL == 1) ? rp * 2 : ((rp & 1) + (rp >> 1) * 4);
    const int tid = threadIdx.x, lane = tid & 63, wv = tid >> 6;
    const int pxh = wv & 1, coq = wv >> 1;
    const int kch = lane >> 5;

    f32x16 acc[2][2][2];   // [row][i(px)][tn]
    #pragma unroll
    for (int r = 0; r < 2; ++r)
        #pragma unroll
        for (int i = 0; i < 2; ++i)
            #pragma unroll
            for (int j = 0; j < 2; ++j)
                #pragma unroll
                for (int k = 0; k < 16; ++k) acc[r][i][j][k] = 0.f;

    auto STAGE = [&](int p, int b) {
        #pragma unroll
        for (int kb = wv; kb < 20; kb += 4) {      // 5 loads per wave
            int slot = kb / 5, pg = kb % 5;
            int pxi = pg * 32 + (lane >> 1);
            int wc = pxi - 16;
            int ir = h0 - DIL + slot * DIL;
            int cg = (lane & 1) ^ ((pxi >> 2) & 1);
            const ushort_t* src;
            if (wc >= 0 && wc < 128 && ir >= 0 && ir < 128)
                src = in + (((size_t)(img * 128 + ir)) * 8 + p) * 2048 + wc * 16 + cg * 8;
            else
                src = zp + lane * 8;
            async16(src, (char*)lds + b * 20480 + kb * 1024);
        }
    };

    STAGE(0, 0);
    #pragma unroll
    for (int p = 0; p < 8; ++p) {
        bf16x8 w0[9], w1[9];
        #pragma unroll
        for (int tap = 0; tap < 9; ++tap) {
            int fbase = (((p >> 1) * 9 + tap) * 2 + (p & 1)) * 4 + coq * 2;
            w0[tap] = *(const bf16x8*)(Wp + ((size_t)fbase * 64 + lane) * 8);
            w1[tap] = *(const bf16x8*)(Wp + ((size_t)(fbase + 1) * 64 + lane) * 8);
        }
        asm volatile("" ::: "memory");
        if (p < 7) STAGE(p + 1, (p + 1) & 1);
        if (p < 7) asm volatile("s_waitcnt vmcnt(23)" ::: "memory");
        else       asm volatile("s_waitcnt vmcnt(18)" ::: "memory");
        __builtin_amdgcn_s_barrier();
        __builtin_amdgcn_s_setprio(1);
        const ushort_t* bbuf = lds + (p & 1) * 10240;
        #pragma unroll
        for (int tap = 0; tap < 9; ++tap) {
            const int tr = tap / 3, tc = tap % 3;
            #pragma unroll
            for (int r = 0; r < 2; ++r) {
                const ushort_t* sb = bbuf + (r + tr) * 2560;
                #pragma unroll
                for (int i = 0; i < 2; ++i) {
                    int pxi = pxh * 64 + i * 32 + (lane & 31) + (tc - 1) * DIL + 16;
                    int s = kch ^ ((pxi >> 2) & 1);
                    bf16x8 bv = *(const bf16x8*)(sb + pxi * 16 + s * 8);
                    acc[r][i][0] = __builtin_amdgcn_mfma_f32_32x32x16_bf16(w0[tap], bv, acc[r][i][0], 0, 0, 0);
                    acc[r][i][1] = __builtin_amdgcn_mfma_f32_32x32x16_bf16(w1[tap], bv, acc[r][i][1], 0, 0, 0);
                }
            }
        }
        __builtin_amdgcn_s_setprio(0);
        __builtin_amdgcn_s_barrier();
    }
    __syncthreads();

    if (MODE == 0 || MODE == 2) {
        #pragma unroll
        for (int r = 0; r < 2; ++r) {
            const int hr = h0 + r * DIL;
            for (int u = tid; u < 2048; u += 256) {
                int px = u >> 4, c8 = (u & 15) * 8;
                size_t soff = (((size_t)(img * 128 + hr)) * 8 + (c8 >> 4)) * 2048 + px * 16 + (c8 & 8);
                *(uint4*)&lds[r * 17408 + px * 136 + c8] = *(const uint4*)&resn[soff];
            }
        }
        __syncthreads();
    }
    #pragma unroll
    for (int r = 0; r < 2; ++r) {
        const int hr = h0 + r * DIL;
        #pragma unroll
        for (int i = 0; i < 2; ++i)
            #pragma unroll
            for (int tn = 0; tn < 2; ++tn)
                #pragma unroll
                for (int rgq = 0; rgq < 4; ++rgq) {
                    const int cob = coq * 64 + tn * 32 + 8 * rgq + 4 * kch;
                    const int px = pxh * 64 + i * 32 + (lane & 31);
                    float v[4];
                    #pragma unroll
                    for (int e = 0; e < 4; ++e) {
                        float t = acc[r][i][tn][rgq * 4 + e] + bias[cob + e];
                        v[e] = (t >= 0.f) ? t : 0.2f * t;
                    }
                    if (MODE == 0) {
                        uint2 rr = *(const uint2*)&lds[r * 17408 + px * 136 + cob];
                        float w0v = bf2f(rr.x & 0xffffu) + v[0];
                        float w1v = bf2f(rr.x >> 16)     + v[1];
                        float w2v = bf2f(rr.y & 0xffffu) + v[2];
                        float w3v = bf2f(rr.y >> 16)     + v[3];
                        uint2 pk;
                        pk.x = f2bf(w0v) | (f2bf(w1v) << 16);
                        pk.y = f2bf(w2v) | (f2bf(w3v) << 16);
                        *(uint2*)&lds[r * 17408 + px * 136 + cob] = pk;
                    } else if (MODE == 1) {
                        uint2 pk;
                        pk.x = f2bf(v[0]) | (f2bf(v[1]) << 16);
                        pk.y = f2bf(v[2]) | (f2bf(v[3]) << 16);
                        *(uint2*)&lds[r * 17408 + px * 136 + cob] = pk;
                    } else {
                        uint2 rr = *(const uint2*)&lds[r * 17408 + px * 136 + cob];
                        float rv[4] = { bf2f(rr.x & 0xffffu), bf2f(rr.x >> 16),
                                        bf2f(rr.y & 0xffffu), bf2f(rr.y >> 16) };
                        #pragma unroll
                        for (int e = 0; e < 4; ++e)
                            outf[(((size_t)(img * 128 + cob + e)) * 128 + hr) * 128 + px] = rv[e] + v[e];
                    }
                }
    }
    if (MODE == 0 || MODE == 1) {
        __syncthreads();
        #pragma unroll
        for (int r = 0; r < 2; ++r) {
            const int hr = h0 + r * DIL;
            for (int u = tid; u < 2048; u += 256) {
                int px = u >> 4, c8 = (u & 15) * 8;
                size_t doff = (((size_t)(img * 128 + hr)) * 8 + (c8 >> 4)) * 2048 + px * 16 + (c8 & 8);
                *(uint4*)&outn[doff] = *(const uint4*)&lds[r * 17408 + px * 136 + c8];
            }
        }
    }
}

// ---------------------------------------------------------------------------
extern "C" void kernel_launch(void* const* d_in, const int* in_sizes, int n_in,
                              void* d_out, int out_size, void* d_ws, size_t ws_size,
                              hipStream_t stream)
{
    const float* x   = (const float*)d_in[0];
    const float* Wq  = (const float*)d_in[1];
    const float* bq  = (const float*)d_in[2];
    const float* Wk  = (const float*)d_in[3];
    const float* bk  = (const float*)d_in[4];
    const float* Wv  = (const float*)d_in[5];
    const float* bv  = (const float*)d_in[6];
    const float* Wo  = (const float*)d_in[7];
    const float* bo  = (const float*)d_in[8];
    const float* Wf1 = (const float*)d_in[9];
    const float* bf1 = (const float*)d_in[10];
    const float* Wf2 = (const float*)d_in[11];
    const float* bf2 = (const float*)d_in[12];
    float* out = (float*)d_out;
    char* ws = (char*)d_ws;
    const size_t MB = 1048576ull;
    ushort_t* qw   = (ushort_t*)(ws);                 // 64 MB; attnc alias; later ff1n
    ushort_t* kw   = (ushort_t*)(ws + 64 * MB);       // 64 MB; later vt; later x1n
    ushort_t* vw   = (ushort_t*)(ws + 128 * MB);      // 64 MB; later attn NHWC-p
    ushort_t* xn   = (ushort_t*)(ws + 192 * MB);      // 64 MB; x NHWC-p (lives to conv1)
    float*    sc   = (float*)   (ws + 256 * MB);      // 17.9 MB
    ushort_t* Wp   = (ushort_t*)(ws + 274 * MB);      // 864 KB
    ushort_t* Wqkv = (ushort_t*)(ws + 275 * MB);      // 96 KB
    ushort_t* zp   = (ushort_t*)(ws + 275 * MB + 256 * 1024);  // 1 KB zeros
    ushort_t* pbf  = (ushort_t*)(ws + 276 * MB);      // 8.95 MB
    ushort_t* attnc = qw;    // attn scale-chunk NCHW (qw dead after scores)
    ushort_t* vt    = kw;    // V^T all scales (kw dead after scores)
    ushort_t* nhwc  = vw;    // attn NHWC-p (vw dead after vtrans)
    ushort_t* x1n   = kw;    // x1 NHWC-p (vt dead after pvm)
    ushort_t* ff1n  = qw;    // ff1 NHWC-p (attnc dead after attn2nhwc)

    hipMemsetAsync(zp, 0, 1024, stream);
    hipMemsetAsync(sc + SC_OFF2, 0, (size_t)(SC_TOT - SC_OFF2) * 4, stream);
    prepack_all_kernel<<<dim3(640, 3), 256, 0, stream>>>(Wo, Wf1, Wf2, Wq, Wk, Wv, Wp, Wqkv);

    // 1) fused transpose + q/k/v (writes xn for conv1 residual)
    qkvm_kernel<<<dim3(128, 16), 768, 0, stream>>>(x, Wqkv, bq, bk, bv, xn, qw, kw, vw);

    // 2) attention
    scores_all_kernel<<<dim3(1024), 256, 0, stream>>>(qw, kw, sc);
    softmax_vtrans_kernel<<<dim3(11584), 256, 0, stream>>>(sc, pbf, vw, vt);
    pvm_all_kernel<<<dim3(4096), 256, 0, stream>>>(pbf, vt, attnc);

    // 3) attn chunks -> NHWC-p (into vw region)
    attn2nhwc_kernel<<<dim3(128, 16), 256, 0, stream>>>(attnc, nhwc);
    // 4) x1 = x + lrelu(conv3x3(attn)) -> x1n NHWC-p (kw region)
    conv3x_kernel<1, 0><<<dim3(64, 16), 256, 0, stream>>>(nhwc, Wp, bo, xn, nullptr, x1n, zp);
    // 5) ff1 = lrelu(conv3x3 dil2(x1)) -> ff1n NHWC-p (qw region)
    conv3x_kernel<2, 1><<<dim3(64, 16), 256, 0, stream>>>(x1n, Wp + 147456, bf1, nullptr, nullptr, ff1n, zp);
    // 6) out = x1 + lrelu(conv3x3(ff1)) -> d_out fp32 NCHW
    conv3x_kernel<1, 2><<<dim3(64, 16), 256, 0, stream>>>(ff1n, Wp + 2 * 147456, bf2, x1n, out, nullptr, zp);
}